// Round 1
// baseline (9602.279 us; speedup 1.0000x reference)
//
#include <hip/hip_runtime.h>
#include <hip/hip_bf16.h>
#include <math.h>

// ---------------- problem constants ----------------
#define BB 4
#define SS 512
#define TT 512
#define DD 512
#define FF 2048
#define HH 8
#define DKK 64
#define NL 6
#define VV 32000
#define MTOK (BB*SS)     // 2048 tokens (same for src and trg)
#define PAD_ID 0

// ---------------- tiled fp32 GEMM ----------------
#define BM 64
#define BN 64
#define BK 16

template<int RELU>
__device__ __forceinline__ void gemm_body(const float* __restrict__ A, int lda,
    const float* __restrict__ Bm, int ldb, float* __restrict__ C, int ldc,
    int K, const float* __restrict__ bias)
{
    __shared__ float As[BK][BM + 1];
    __shared__ float Bs[BK][BN + 1];
    const int tid = threadIdx.x;
    const int tx = tid & 15;       // 0..15 -> n
    const int ty = tid >> 4;       // 0..15 -> m
    const int row0 = blockIdx.y * BM;
    const int col0 = blockIdx.x * BN;
    float acc[4][4] = {};

    for (int k0 = 0; k0 < K; k0 += BK) {
        #pragma unroll
        for (int i = 0; i < 4; i++) {
            int lin = tid + i * 256;
            int m  = lin >> 4;
            int kk = lin & 15;
            As[kk][m] = A[(size_t)(row0 + m) * lda + k0 + kk];
        }
        #pragma unroll
        for (int i = 0; i < 4; i++) {
            int lin = tid + i * 256;
            int n  = lin & 63;
            int kk = lin >> 6;
            Bs[kk][n] = Bm[(size_t)(k0 + kk) * ldb + col0 + n];
        }
        __syncthreads();
        #pragma unroll
        for (int kk = 0; kk < BK; kk++) {
            float a[4], bb[4];
            #pragma unroll
            for (int i = 0; i < 4; i++) a[i] = As[kk][ty * 4 + i];
            #pragma unroll
            for (int j = 0; j < 4; j++) bb[j] = Bs[kk][tx * 4 + j];
            #pragma unroll
            for (int i = 0; i < 4; i++)
                #pragma unroll
                for (int j = 0; j < 4; j++)
                    acc[i][j] = fmaf(a[i], bb[j], acc[i][j]);
        }
        __syncthreads();
    }

    #pragma unroll
    for (int i = 0; i < 4; i++) {
        size_t r = (size_t)(row0 + ty * 4 + i);
        #pragma unroll
        for (int j = 0; j < 4; j++) {
            int c = col0 + tx * 4 + j;
            float val = acc[i][j];
            if (bias) val += bias[c];
            if (RELU) val = fmaxf(val, 0.0f);
            C[r * ldc + c] = val;
        }
    }
}

__global__ __launch_bounds__(256) void gemm_kernel(const float* __restrict__ A, int lda,
    const float* __restrict__ Bm, int ldb, float* __restrict__ C, int ldc,
    int K, const float* __restrict__ bias, int relu)
{
    if (relu) gemm_body<1>(A, lda, Bm, ldb, C, ldc, K, bias);
    else      gemm_body<0>(A, lda, Bm, ldb, C, ldc, K, bias);
}

// attn @ V : one (b,h) batch per blockIdx.z.  P is [BH][S][S], V/CTX are [tok][512].
__global__ __launch_bounds__(256) void pv_kernel(const float* __restrict__ P,
    const float* __restrict__ Vm, float* __restrict__ CTX)
{
    int bh = blockIdx.z;
    int b = bh >> 3, h = bh & 7;
    const float* A  = P  + (size_t)bh * SS * SS;
    const float* Bm = Vm + (size_t)b * SS * (HH * DKK) + h * DKK;
    float* C        = CTX + (size_t)b * SS * (HH * DKK) + h * DKK;
    gemm_body<0>(A, SS, Bm, HH * DKK, C, HH * DKK, SS, nullptr);
}

// ---------------- QK^T ----------------
// scores[bh][sq][sk] = sum_e Q[b,sq,h,e] * K[b,sk,h,e]   (raw, unscaled, unmasked)
__global__ __launch_bounds__(256) void qk_kernel(const float* __restrict__ Q,
    const float* __restrict__ Km, float* __restrict__ P)
{
    __shared__ float Qs[64][DKK + 1];
    __shared__ float Ks[64][DKK + 1];
    int bh = blockIdx.z;
    int b = bh >> 3, h = bh & 7;
    const float* Qb = Q  + (size_t)b * SS * (HH * DKK) + h * DKK;
    const float* Kb = Km + (size_t)b * SS * (HH * DKK) + h * DKK;
    float* Pb = P + (size_t)bh * SS * SS;
    int tid = threadIdx.x;
    int tx = tid & 15, ty = tid >> 4;
    int sq0 = blockIdx.y * 64, sk0 = blockIdx.x * 64;

    #pragma unroll
    for (int i = 0; i < 16; i++) {
        int lin = tid + i * 256;
        int r = lin >> 6, e = lin & 63;
        Qs[r][e] = Qb[(size_t)(sq0 + r) * (HH * DKK) + e];
        Ks[r][e] = Kb[(size_t)(sk0 + r) * (HH * DKK) + e];
    }
    __syncthreads();

    float acc[4][4] = {};
    #pragma unroll 8
    for (int e = 0; e < DKK; e++) {
        float a[4], bb[4];
        #pragma unroll
        for (int i = 0; i < 4; i++) a[i] = Qs[ty * 4 + i][e];
        #pragma unroll
        for (int j = 0; j < 4; j++) bb[j] = Ks[tx * 4 + j][e];
        #pragma unroll
        for (int i = 0; i < 4; i++)
            #pragma unroll
            for (int j = 0; j < 4; j++)
                acc[i][j] = fmaf(a[i], bb[j], acc[i][j]);
    }
    #pragma unroll
    for (int i = 0; i < 4; i++)
        #pragma unroll
        for (int j = 0; j < 4; j++)
            Pb[(size_t)(sq0 + ty * 4 + i) * SS + sk0 + tx * 4 + j] = acc[i][j];
}

// ---------------- softmax with mask (in place on P) ----------------
// grid: BH*S blocks (one row each), 256 threads.
__global__ __launch_bounds__(256) void softmax_kernel(float* __restrict__ P,
    const int* __restrict__ ids, int causal)
{
    int idx = blockIdx.x;            // bh*S + sq
    int sq = idx & (SS - 1);
    int bh = idx >> 9;
    int b = bh >> 3;
    float* row = P + (size_t)idx * SS;
    int tid = threadIdx.x;
    __shared__ float sbuf[4];

    float v[2];
    float lmax = -1e30f;
    #pragma unroll
    for (int i = 0; i < 2; i++) {
        int sk = tid + i * 256;
        float s = row[sk] * 0.125f;   // DK^-0.5
        bool m = (ids[b * SS + sk] == PAD_ID) || (causal && sk > sq);
        v[i] = m ? -1e30f : s;
        lmax = fmaxf(lmax, v[i]);
    }
    #pragma unroll
    for (int o = 32; o > 0; o >>= 1) lmax = fmaxf(lmax, __shfl_down(lmax, o));
    if ((tid & 63) == 0) sbuf[tid >> 6] = lmax;
    __syncthreads();
    lmax = fmaxf(fmaxf(sbuf[0], sbuf[1]), fmaxf(sbuf[2], sbuf[3]));
    __syncthreads();

    float lsum = 0.0f;
    #pragma unroll
    for (int i = 0; i < 2; i++) { v[i] = __expf(v[i] - lmax); lsum += v[i]; }
    #pragma unroll
    for (int o = 32; o > 0; o >>= 1) lsum += __shfl_down(lsum, o);
    if ((tid & 63) == 0) sbuf[tid >> 6] = lsum;
    __syncthreads();
    lsum = sbuf[0] + sbuf[1] + sbuf[2] + sbuf[3];
    float inv = 1.0f / lsum;
    #pragma unroll
    for (int i = 0; i < 2; i++) row[tid + i * 256] = v[i] * inv;
}

// ---------------- residual add + LayerNorm (in place on x) ----------------
// grid: MTOK blocks, 256 threads, D = 512 (2 elems/thread)
__global__ __launch_bounds__(256) void add_ln_kernel(float* __restrict__ x,
    const float* __restrict__ addv, const float* __restrict__ g,
    const float* __restrict__ bta)
{
    int row = blockIdx.x;
    int tid = threadIdx.x;
    size_t base = (size_t)row * DD;
    __shared__ float sbuf[4];

    float v0 = x[base + tid]       + addv[base + tid];
    float v1 = x[base + tid + 256] + addv[base + tid + 256];

    float s = v0 + v1;
    #pragma unroll
    for (int o = 32; o > 0; o >>= 1) s += __shfl_down(s, o);
    if ((tid & 63) == 0) sbuf[tid >> 6] = s;
    __syncthreads();
    float mean = (sbuf[0] + sbuf[1] + sbuf[2] + sbuf[3]) * (1.0f / DD);
    __syncthreads();

    float d0 = v0 - mean, d1 = v1 - mean;
    float ss = d0 * d0 + d1 * d1;
    #pragma unroll
    for (int o = 32; o > 0; o >>= 1) ss += __shfl_down(ss, o);
    if ((tid & 63) == 0) sbuf[tid >> 6] = ss;
    __syncthreads();
    float var = (sbuf[0] + sbuf[1] + sbuf[2] + sbuf[3]) * (1.0f / DD);
    float inv = rsqrtf(var + 1e-5f);

    x[base + tid]       = d0 * inv * g[tid]       + bta[tid];
    x[base + tid + 256] = d1 * inv * g[tid + 256] + bta[tid + 256];
}

// ---------------- embedding + sinusoidal PE ----------------
// grid: MTOK blocks, 512 threads
__global__ void embed_kernel(const int* __restrict__ ids,
    const float* __restrict__ emb, float* __restrict__ out)
{
    int tok = blockIdx.x;
    int d = threadIdx.x;
    int pos = tok & (SS - 1);
    int id = ids[tok];
    int i = d >> 1;
    double freq = exp(-(2.0 * (double)i / (double)DD) * log(10000.0));
    double ang = (double)pos * freq;
    float pe = (float)((d & 1) ? cos(ang) : sin(ang));
    out[(size_t)tok * DD + d] = emb[(size_t)id * DD + d] * 22.62741699796952f + pe;
}

// ---------------- host orchestration ----------------
extern "C" void kernel_launch(void* const* d_in, const int* in_sizes, int n_in,
                              void* d_out, int out_size, void* d_ws, size_t ws_size,
                              hipStream_t stream)
{
    (void)in_sizes; (void)n_in; (void)out_size; (void)ws_size;

    const int*   src      = (const int*)  d_in[0];
    const int*   trg      = (const int*)  d_in[1];
    const float* emb_src  = (const float*)d_in[2];
    const float* emb_trg  = (const float*)d_in[3];
    const float* enc_wq   = (const float*)d_in[4];
    const float* enc_wk   = (const float*)d_in[5];
    const float* enc_wv   = (const float*)d_in[6];
    const float* enc_wo   = (const float*)d_in[7];
    const float* enc_ln1g = (const float*)d_in[8];
    const float* enc_ln1b = (const float*)d_in[9];
    const float* enc_w1   = (const float*)d_in[10];
    const float* enc_b1   = (const float*)d_in[11];
    const float* enc_w2   = (const float*)d_in[12];
    const float* enc_b2   = (const float*)d_in[13];
    const float* enc_ln2g = (const float*)d_in[14];
    const float* enc_ln2b = (const float*)d_in[15];
    const float* dec_wq   = (const float*)d_in[16];
    const float* dec_wk   = (const float*)d_in[17];
    const float* dec_wv   = (const float*)d_in[18];
    const float* dec_wo   = (const float*)d_in[19];
    const float* dec_ln1g = (const float*)d_in[20];
    const float* dec_ln1b = (const float*)d_in[21];
    const float* dec_cq   = (const float*)d_in[22];
    const float* dec_ck   = (const float*)d_in[23];
    const float* dec_cv   = (const float*)d_in[24];
    const float* dec_co   = (const float*)d_in[25];
    const float* dec_ln2g = (const float*)d_in[26];
    const float* dec_ln2b = (const float*)d_in[27];
    const float* dec_w1   = (const float*)d_in[28];
    const float* dec_b1   = (const float*)d_in[29];
    const float* dec_w2   = (const float*)d_in[30];
    const float* dec_b2   = (const float*)d_in[31];
    const float* dec_ln3g = (const float*)d_in[32];
    const float* dec_ln3b = (const float*)d_in[33];
    const float* proj     = (const float*)d_in[34];

    float* OUT = (float*)d_out;
    float* ws0 = (float*)d_ws;

    const size_t MSZ = (size_t)MTOK * DD;   // 1,048,576 floats
    float* X   = ws0;
    float* Yb  = ws0 + 1 * MSZ;
    float* Qb  = ws0 + 2 * MSZ;
    float* Kb  = ws0 + 3 * MSZ;
    float* Vb  = ws0 + 4 * MSZ;
    float* CTX = ws0 + 5 * MSZ;
    float* T1  = ws0 + 6 * MSZ;
    float* HFF = ws0 + 7 * MSZ;             // 4*MSZ floats
    float* P   = ws0 + 11 * MSZ;            // 8*MSZ floats (B*H*S*S)

    auto run_gemm = [&](const float* A, int lda, const float* W, int ldb,
                        float* C, int ldc, int Mv, int Nv, int Kv,
                        const float* bias, int relu) {
        dim3 g(Nv / BN, Mv / BM, 1);
        gemm_kernel<<<g, 256, 0, stream>>>(A, lda, W, ldb, C, ldc, Kv, bias, relu);
    };

    // full MHA block: writes attention output (pre-residual) into T1
    auto attn = [&](const float* xq, const float* xkv,
                    const float* wq_, const float* wk_, const float* wv_,
                    const float* wo_, const int* mask_ids, int causal) {
        run_gemm(xq,  DD, wq_, DD, Qb, DD, MTOK, DD, DD, nullptr, 0);
        run_gemm(xkv, DD, wk_, DD, Kb, DD, MTOK, DD, DD, nullptr, 0);
        run_gemm(xkv, DD, wv_, DD, Vb, DD, MTOK, DD, DD, nullptr, 0);
        qk_kernel<<<dim3(SS / 64, SS / 64, BB * HH), 256, 0, stream>>>(Qb, Kb, P);
        softmax_kernel<<<BB * HH * SS, 256, 0, stream>>>(P, mask_ids, causal);
        pv_kernel<<<dim3(1, SS / 64, BB * HH), 256, 0, stream>>>(P, Vb, CTX);
        run_gemm(CTX, DD, wo_, DD, T1, DD, MTOK, DD, DD, nullptr, 0);
    };

    // ---- encoder ----
    embed_kernel<<<MTOK, DD, 0, stream>>>(src, emb_src, X);
    for (int l = 0; l < NL; l++) {
        const size_t woff = (size_t)l * DD * DD;
        attn(X, X, enc_wq + woff, enc_wk + woff, enc_wv + woff, enc_wo + woff, src, 0);
        add_ln_kernel<<<MTOK, 256, 0, stream>>>(X, T1, enc_ln1g + l * DD, enc_ln1b + l * DD);
        run_gemm(X, DD, enc_w1 + (size_t)l * DD * FF, FF, HFF, FF, MTOK, FF, DD, enc_b1 + l * FF, 1);
        run_gemm(HFF, FF, enc_w2 + (size_t)l * FF * DD, DD, T1, DD, MTOK, DD, FF, enc_b2 + l * DD, 0);
        add_ln_kernel<<<MTOK, 256, 0, stream>>>(X, T1, enc_ln2g + l * DD, enc_ln2b + l * DD);
    }

    // ---- decoder ----
    embed_kernel<<<MTOK, DD, 0, stream>>>(trg, emb_trg, Yb);
    for (int l = 0; l < NL; l++) {
        const size_t woff = (size_t)l * DD * DD;
        // masked self-attention
        attn(Yb, Yb, dec_wq + woff, dec_wk + woff, dec_wv + woff, dec_wo + woff, trg, 1);
        add_ln_kernel<<<MTOK, 256, 0, stream>>>(Yb, T1, dec_ln1g + l * DD, dec_ln1b + l * DD);
        // cross-attention (queries from decoder, keys/values from encoder output)
        attn(Yb, X, dec_cq + woff, dec_ck + woff, dec_cv + woff, dec_co + woff, src, 0);
        add_ln_kernel<<<MTOK, 256, 0, stream>>>(Yb, T1, dec_ln2g + l * DD, dec_ln2b + l * DD);
        // FFN
        run_gemm(Yb, DD, dec_w1 + (size_t)l * DD * FF, FF, HFF, FF, MTOK, FF, DD, dec_b1 + l * FF, 1);
        run_gemm(HFF, FF, dec_w2 + (size_t)l * FF * DD, DD, T1, DD, MTOK, DD, FF, dec_b2 + l * DD, 0);
        add_ln_kernel<<<MTOK, 256, 0, stream>>>(Yb, T1, dec_ln3g + l * DD, dec_ln3b + l * DD);
    }

    // ---- final vocab projection ----
    run_gemm(Yb, DD, proj, VV, OUT, VV, MTOK, VV, DD, nullptr, 0);
}

// Round 2
// 2837.734 us; speedup vs baseline: 3.3838x; 3.3838x over previous
//
#include <hip/hip_runtime.h>
#include <math.h>

// ---------------- problem constants ----------------
#define BBATCH 4
#define SS 512
#define DDIM 512
#define FFN 2048
#define NHEAD 8
#define DHEAD 64
#define NL 6
#define NVOC 32000
#define MTOK (BBATCH*SS)       // 2048
#define PAD_ID 0

typedef unsigned short u16;
typedef __attribute__((ext_vector_type(8))) short short8;   // 8 bf16 (4 VGPRs)
typedef __attribute__((ext_vector_type(4))) float f32x4;

__device__ __forceinline__ u16 f2bf(float f) {
    union { float f; unsigned u; } v; v.f = f;
    unsigned r = ((v.u >> 16) & 1u) + 0x7fffu;   // round-to-nearest-even
    return (u16)((v.u + r) >> 16);
}

__device__ __forceinline__ void gload16(const u16* g, u16* l) {
    __builtin_amdgcn_global_load_lds(
        (const __attribute__((address_space(1))) void*)g,
        (__attribute__((address_space(3))) void*)l, 16, 0, 0);
}

// ======================= MFMA GEMM (NT): C[M,N] = A[M,K] * B[N,K]^T =======================
// A, B bf16 row-major with k contiguous; C fp32 or bf16. 256 threads = 4 waves in 2x2.
// Batched via blockIdx.z decomposed as (zb = z>>3, zh = z&7) with per-axis strides.
// LDS tiles store [row][32k] with 16B-slot XOR swizzle: phys_slot = slot ^ ((row&3)<<4).
template<int BM, int BN, int OUTBF, int RELU, int BIAS>
__global__ __launch_bounds__(256) void mgemm(
    const u16* __restrict__ A, int lda, size_t aSb, size_t aSh,
    const u16* __restrict__ B, int ldb, size_t bSb, size_t bSh,
    void* __restrict__ Cv, int ldc, size_t cSb, size_t cSh,
    int K, const float* __restrict__ bias)
{
    static_assert(BM % 64 == 0 && BN % 64 == 0, "tile");
    __shared__ __align__(16) u16 As[BM * 32];
    __shared__ __align__(16) u16 Bs[BN * 32];

    const int tid  = threadIdx.x;
    const int lane = tid & 63;
    const int wid  = tid >> 6;
    const int wr   = wid >> 1, wc = wid & 1;
    const int row0 = blockIdx.y * BM, col0 = blockIdx.x * BN;
    const int zb = blockIdx.z >> 3, zh = blockIdx.z & 7;
    A += (size_t)zb * aSb + (size_t)zh * aSh;
    B += (size_t)zb * bSb + (size_t)zh * bSh;

    constexpr int MF = BM / 32;     // m-frags per wave
    constexpr int NF = BN / 32;     // n-frags per wave
    constexpr int RA = BM / 64;     // A staging rounds (4KB each)
    constexpr int RB = BN / 64;

    // staging sources: dest byte idx = r*4096 + tid*16 -> row = tid/4 + r*64,
    // phys slot = (tid&3)*16; logical k-slot = phys ^ ((row&3)<<4)
    const u16* aSrc[RA]; u16* aDst[RA];
    #pragma unroll
    for (int r = 0; r < RA; r++) {
        int row = (tid >> 2) + r * 64;
        int slot = ((tid & 3) << 4) ^ ((row & 3) << 4);
        aSrc[r] = A + (size_t)(row0 + row) * lda + (slot >> 1);
        aDst[r] = &As[r * 2048 + tid * 8];
    }
    const u16* bSrc[RB]; u16* bDst[RB];
    #pragma unroll
    for (int r = 0; r < RB; r++) {
        int row = (tid >> 2) + r * 64;
        int slot = ((tid & 3) << 4) ^ ((row & 3) << 4);
        bSrc[r] = B + (size_t)(col0 + row) * ldb + (slot >> 1);
        bDst[r] = &Bs[r * 2048 + tid * 8];
    }

    f32x4 acc[MF][NF];
    const f32x4 zero = {0.f, 0.f, 0.f, 0.f};
    #pragma unroll
    for (int m = 0; m < MF; m++)
        #pragma unroll
        for (int n = 0; n < NF; n++) acc[m][n] = zero;

    for (int k0 = 0; k0 < K; k0 += 32) {
        #pragma unroll
        for (int r = 0; r < RA; r++) gload16(aSrc[r] + k0, aDst[r]);
        #pragma unroll
        for (int r = 0; r < RB; r++) gload16(bSrc[r] + k0, bDst[r]);
        __syncthreads();   // drains vmcnt before barrier

        short8 af[MF], bf[NF];
        #pragma unroll
        for (int m = 0; m < MF; m++) {
            int row = wr * (BM / 2) + m * 16 + (lane & 15);
            int slot = ((lane >> 4) << 4) ^ ((row & 3) << 4);
            af[m] = *(const short8*)&As[row * 32 + (slot >> 1)];
        }
        #pragma unroll
        for (int n = 0; n < NF; n++) {
            int row = wc * (BN / 2) + n * 16 + (lane & 15);
            int slot = ((lane >> 4) << 4) ^ ((row & 3) << 4);
            bf[n] = *(const short8*)&Bs[row * 32 + (slot >> 1)];
        }
        #pragma unroll
        for (int m = 0; m < MF; m++)
            #pragma unroll
            for (int n = 0; n < NF; n++)
                acc[m][n] = __builtin_amdgcn_mfma_f32_16x16x32_bf16(af[m], bf[n], acc[m][n], 0, 0, 0);
        __syncthreads();
    }

    // epilogue: C/D layout col = lane&15, row = (lane>>4)*4 + i
    const int crow = row0 + wr * (BM / 2);
    const int ccol = col0 + wc * (BN / 2);
    #pragma unroll
    for (int m = 0; m < MF; m++) {
        #pragma unroll
        for (int n = 0; n < NF; n++) {
            int col = ccol + n * 16 + (lane & 15);
            float bv = BIAS ? bias[col] : 0.0f;
            #pragma unroll
            for (int i = 0; i < 4; i++) {
                int row = crow + m * 16 + ((lane >> 4) << 2) + i;
                float v = acc[m][n][i] + bv;
                if (RELU) v = fmaxf(v, 0.0f);
                if (OUTBF) {
                    u16* C = (u16*)Cv + (size_t)zb * cSb + (size_t)zh * cSh;
                    C[(size_t)row * ldc + col] = f2bf(v);
                } else {
                    float* C = (float*)Cv + (size_t)zb * cSb + (size_t)zh * cSh;
                    C[(size_t)row * ldc + col] = v;
                }
            }
        }
    }
}

// ============ weight transpose + fp32->bf16 convert:  dst[N,K] = bf16(src[K,N]) ============
__global__ __launch_bounds__(256) void transp(const float* __restrict__ src, u16* __restrict__ dst,
                                              int N, int K, size_t sStride, size_t dStride)
{
    src += (size_t)blockIdx.z * sStride;
    dst += (size_t)blockIdx.z * dStride;
    __shared__ u16 t[64][65];
    const int tid = threadIdx.x;
    const int n0 = blockIdx.x * 64, k0 = blockIdx.y * 64;
    #pragma unroll
    for (int i = 0; i < 16; i++) {
        int idx = tid + i * 256;
        int kr = idx >> 6, nc = idx & 63;
        t[kr][nc] = f2bf(src[(size_t)(k0 + kr) * N + n0 + nc]);
    }
    __syncthreads();
    #pragma unroll
    for (int i = 0; i < 16; i++) {
        int idx = tid + i * 256;
        int nr = idx >> 6, kc = idx & 63;
        dst[(size_t)(n0 + nr) * K + k0 + kc] = t[kc][nr];
    }
}

// ============ embedding + sinusoidal PE (fp32 + bf16 shadow) ============
__global__ void embed_kernel(const int* __restrict__ ids, const float* __restrict__ emb,
                             float* __restrict__ out, u16* __restrict__ outb)
{
    int tok = blockIdx.x;
    int d = threadIdx.x;
    int pos = tok & (SS - 1);
    int id = ids[tok];
    int i = d >> 1;
    double freq = exp(-(2.0 * (double)i / (double)DDIM) * log(10000.0));
    double ang = (double)pos * freq;
    float pe = (float)((d & 1) ? cos(ang) : sin(ang));
    float val = emb[(size_t)id * DDIM + d] * 22.62741699796952f + pe;
    out[(size_t)tok * DDIM + d] = val;
    outb[(size_t)tok * DDIM + d] = f2bf(val);
}

// ============ masked softmax: fp32 scores -> bf16 probs ============
__global__ __launch_bounds__(256) void softmax_kernel(const float* __restrict__ S,
    u16* __restrict__ P, const int* __restrict__ ids, int causal)
{
    int idx = blockIdx.x;            // bh*512 + sq
    int sq = idx & (SS - 1);
    int bh = idx >> 9;
    int b = bh >> 3;
    const float* row = S + (size_t)idx * SS;
    u16* prow = P + (size_t)idx * SS;
    int tid = threadIdx.x;
    __shared__ float sbuf[4];

    float v[2];
    float lmax = -1e30f;
    #pragma unroll
    for (int i = 0; i < 2; i++) {
        int sk = tid + i * 256;
        float s = row[sk] * 0.125f;
        bool m = (ids[b * SS + sk] == PAD_ID) || (causal && sk > sq);
        v[i] = m ? -1e30f : s;
        lmax = fmaxf(lmax, v[i]);
    }
    #pragma unroll
    for (int o = 32; o > 0; o >>= 1) lmax = fmaxf(lmax, __shfl_down(lmax, o));
    if ((tid & 63) == 0) sbuf[tid >> 6] = lmax;
    __syncthreads();
    lmax = fmaxf(fmaxf(sbuf[0], sbuf[1]), fmaxf(sbuf[2], sbuf[3]));
    __syncthreads();

    float lsum = 0.0f;
    #pragma unroll
    for (int i = 0; i < 2; i++) { v[i] = __expf(v[i] - lmax); lsum += v[i]; }
    #pragma unroll
    for (int o = 32; o > 0; o >>= 1) lsum += __shfl_down(lsum, o);
    if ((tid & 63) == 0) sbuf[tid >> 6] = lsum;
    __syncthreads();
    lsum = sbuf[0] + sbuf[1] + sbuf[2] + sbuf[3];
    float inv = 1.0f / lsum;
    #pragma unroll
    for (int i = 0; i < 2; i++) prow[tid + i * 256] = f2bf(v[i] * inv);
}

// ============ residual add + LayerNorm (fp32 in place, bf16 shadow out) ============
__global__ __launch_bounds__(256) void add_ln_kernel(float* __restrict__ x,
    const float* __restrict__ addv, const float* __restrict__ g,
    const float* __restrict__ bta, u16* __restrict__ xb)
{
    int row = blockIdx.x;
    int tid = threadIdx.x;
    size_t base = (size_t)row * DDIM;
    __shared__ float sbuf[4];

    float v0 = x[base + tid]       + addv[base + tid];
    float v1 = x[base + tid + 256] + addv[base + tid + 256];

    float s = v0 + v1;
    #pragma unroll
    for (int o = 32; o > 0; o >>= 1) s += __shfl_down(s, o);
    if ((tid & 63) == 0) sbuf[tid >> 6] = s;
    __syncthreads();
    float mean = (sbuf[0] + sbuf[1] + sbuf[2] + sbuf[3]) * (1.0f / DDIM);
    __syncthreads();

    float d0 = v0 - mean, d1 = v1 - mean;
    float ss = d0 * d0 + d1 * d1;
    #pragma unroll
    for (int o = 32; o > 0; o >>= 1) ss += __shfl_down(ss, o);
    if ((tid & 63) == 0) sbuf[tid >> 6] = ss;
    __syncthreads();
    float var = (sbuf[0] + sbuf[1] + sbuf[2] + sbuf[3]) * (1.0f / DDIM);
    float inv = rsqrtf(var + 1e-5f);

    float o0 = d0 * inv * g[tid]       + bta[tid];
    float o1 = d1 * inv * g[tid + 256] + bta[tid + 256];
    x[base + tid] = o0;
    x[base + tid + 256] = o1;
    xb[base + tid] = f2bf(o0);
    xb[base + tid + 256] = f2bf(o1);
}

// ======================= host orchestration =======================
// per-layer weight-block layout (u16 offsets)
#define OFF_QK 0u            // [1024][512]  (wq_t rows 0-511, wk_t rows 512-1023)
#define OFF_WV 524288u       // [512][512]
#define OFF_WO 786432u
#define OFF_CQ 1048576u
#define OFF_CK 1310720u
#define OFF_CV 1572864u
#define OFF_CO 1835008u
#define OFF_W1 2097152u      // [2048][512]
#define OFF_W2 3145728u      // [512][2048]
#define WBLK   4194304u      // u16 per layer block

extern "C" void kernel_launch(void* const* d_in, const int* in_sizes, int n_in,
                              void* d_out, int out_size, void* d_ws, size_t ws_size,
                              hipStream_t stream)
{
    (void)in_sizes; (void)n_in; (void)out_size;

    const int*   src      = (const int*)  d_in[0];
    const int*   trg      = (const int*)  d_in[1];
    const float* emb_src  = (const float*)d_in[2];
    const float* emb_trg  = (const float*)d_in[3];
    const float* enc_wq   = (const float*)d_in[4];
    const float* enc_wk   = (const float*)d_in[5];
    const float* enc_wv   = (const float*)d_in[6];
    const float* enc_wo   = (const float*)d_in[7];
    const float* enc_ln1g = (const float*)d_in[8];
    const float* enc_ln1b = (const float*)d_in[9];
    const float* enc_w1   = (const float*)d_in[10];
    const float* enc_b1   = (const float*)d_in[11];
    const float* enc_w2   = (const float*)d_in[12];
    const float* enc_b2   = (const float*)d_in[13];
    const float* enc_ln2g = (const float*)d_in[14];
    const float* enc_ln2b = (const float*)d_in[15];
    const float* dec_wq   = (const float*)d_in[16];
    const float* dec_wk   = (const float*)d_in[17];
    const float* dec_wv   = (const float*)d_in[18];
    const float* dec_wo   = (const float*)d_in[19];
    const float* dec_ln1g = (const float*)d_in[20];
    const float* dec_ln1b = (const float*)d_in[21];
    const float* dec_cq   = (const float*)d_in[22];
    const float* dec_ck   = (const float*)d_in[23];
    const float* dec_cv   = (const float*)d_in[24];
    const float* dec_co   = (const float*)d_in[25];
    const float* dec_ln2g = (const float*)d_in[26];
    const float* dec_ln2b = (const float*)d_in[27];
    const float* dec_w1   = (const float*)d_in[28];
    const float* dec_b1   = (const float*)d_in[29];
    const float* dec_w2   = (const float*)d_in[30];
    const float* dec_b2   = (const float*)d_in[31];
    const float* dec_ln3g = (const float*)d_in[32];
    const float* dec_ln3b = (const float*)d_in[33];
    const float* proj     = (const float*)d_in[34];

    float* OUT = (float*)d_out;
    char* base = (char*)d_ws;

    const size_t MSZ = (size_t)MTOK * DDIM;          // 1M elements
    size_t off = 0;
    auto carve = [&](size_t bytes) { char* p = base + off; off += (bytes + 255) & ~(size_t)255; return p; };

    float* X      = (float*)carve(MSZ * 4);
    float* Yb     = (float*)carve(MSZ * 4);
    float* T1     = (float*)carve(MSZ * 4);
    u16*   Xb     = (u16*)  carve(MSZ * 2);
    u16*   Ybf    = (u16*)  carve(MSZ * 2);
    u16*   QKb    = (u16*)  carve((size_t)MTOK * 1024 * 2);      // Q|K packed, ldc 1024
    u16*   Vt     = (u16*)  carve((size_t)512 * MTOK * 2);       // V^T [512][2048]
    u16*   CTX    = (u16*)  carve(MSZ * 2);
    u16*   HFF    = (u16*)  carve((size_t)MTOK * FFN * 2);
    float* SCORES = (float*)carve((size_t)32 * SS * SS * 4);     // 32 MB
    u16*   Pb     = (u16*)  carve((size_t)32 * SS * SS * 2);     // 16 MB
    u16*   projT  = (u16*)SCORES;                                 // overlay (used only at the end)

    const size_t WFULL_B = (size_t)12 * WBLK * 2;
    bool full = (ws_size >= off + WFULL_B);
    u16* Wreg = (u16*)carve(full ? WFULL_B : (size_t)WBLK * 2);

    auto T = [&](const float* s, u16* d, int Kd, int Nd, size_t ss, size_t ds, int L) {
        transp<<<dim3(Nd / 64, Kd / 64, L), 256, 0, stream>>>(s, d, Nd, Kd, ss, ds);
    };

    if (full) {
        const size_t M2 = 512 * 512, MF1 = (size_t)512 * 2048;
        T(enc_wq, Wreg + OFF_QK,          512, 512,  M2, WBLK, NL);
        T(enc_wk, Wreg + OFF_QK + 262144, 512, 512,  M2, WBLK, NL);
        T(enc_wv, Wreg + OFF_WV,          512, 512,  M2, WBLK, NL);
        T(enc_wo, Wreg + OFF_WO,          512, 512,  M2, WBLK, NL);
        T(enc_w1, Wreg + OFF_W1,          512, 2048, MF1, WBLK, NL);
        T(enc_w2, Wreg + OFF_W2,          2048, 512, MF1, WBLK, NL);
        u16* Wd = Wreg + (size_t)NL * WBLK;
        T(dec_wq, Wd + OFF_QK,          512, 512,  M2, WBLK, NL);
        T(dec_wk, Wd + OFF_QK + 262144, 512, 512,  M2, WBLK, NL);
        T(dec_wv, Wd + OFF_WV,          512, 512,  M2, WBLK, NL);
        T(dec_wo, Wd + OFF_WO,          512, 512,  M2, WBLK, NL);
        T(dec_cq, Wd + OFF_CQ,          512, 512,  M2, WBLK, NL);
        T(dec_ck, Wd + OFF_CK,          512, 512,  M2, WBLK, NL);
        T(dec_cv, Wd + OFF_CV,          512, 512,  M2, WBLK, NL);
        T(dec_co, Wd + OFF_CO,          512, 512,  M2, WBLK, NL);
        T(dec_w1, Wd + OFF_W1,          512, 2048, MF1, WBLK, NL);
        T(dec_w2, Wd + OFF_W2,          2048, 512, MF1, WBLK, NL);
    }

    // ---- strides for batched attention gemms (element units) ----
    const size_t qkSb = (size_t)SS * 1024, scSb = (size_t)8 * SS * SS, scSh = (size_t)SS * SS;

    // attention block: inputs (bf16 q-src, bf16 kv-src), weight offsets, mask ids, causal
    auto attn = [&](const u16* qsrc, const u16* kvsrc, const u16* wq_t, const u16* wk_t,
                    const u16* wv_t, const u16* wo_t, float* outT1,
                    const int* mask_ids, int causal, bool fusedQK) {
        if (fusedQK) {
            // QKb[:, 0:1024] = [q|k]
            mgemm<128,128,1,0,0><<<dim3(8, 16, 1), 256, 0, stream>>>(
                qsrc, 512, 0, 0, wq_t, 512, 0, 0, QKb, 1024, 0, 0, 512, nullptr);
        } else {
            mgemm<128,128,1,0,0><<<dim3(4, 16, 1), 256, 0, stream>>>(
                qsrc, 512, 0, 0, wq_t, 512, 0, 0, QKb, 1024, 0, 0, 512, nullptr);
            mgemm<128,128,1,0,0><<<dim3(4, 16, 1), 256, 0, stream>>>(
                kvsrc, 512, 0, 0, wk_t, 512, 0, 0, QKb + 512, 1024, 0, 0, 512, nullptr);
        }
        // V^T[512][2048] = wv_t @ kv^T
        mgemm<128,128,1,0,0><<<dim3(16, 4, 1), 256, 0, stream>>>(
            wv_t, 512, 0, 0, kvsrc, 512, 0, 0, Vt, MTOK, 0, 0, 512, nullptr);
        // scores[bh][sq][sk]
        mgemm<128,128,0,0,0><<<dim3(4, 4, 32), 256, 0, stream>>>(
            QKb, 1024, qkSb, 64, QKb + 512, 1024, qkSb, 64,
            SCORES, SS, scSb, scSh, 64, nullptr);
        softmax_kernel<<<32 * SS, 256, 0, stream>>>(SCORES, Pb, mask_ids, causal);
        // CTX[tok][h*64+e] = P @ V
        mgemm<128,64,1,0,0><<<dim3(1, 4, 32), 256, 0, stream>>>(
            Pb, SS, scSb, scSh, Vt, MTOK, 512, (size_t)64 * MTOK,
            CTX, 512, (size_t)SS * 512, 64, SS, nullptr);
        // out = CTX @ wo^T
        mgemm<128,128,0,0,0><<<dim3(4, 16, 1), 256, 0, stream>>>(
            CTX, 512, 0, 0, wo_t, 512, 0, 0, outT1, 512, 0, 0, 512, nullptr);
    };

    // ---- encoder ----
    embed_kernel<<<MTOK, DDIM, 0, stream>>>(src, emb_src, X, Xb);
    for (int l = 0; l < NL; l++) {
        u16* wb;
        if (full) wb = Wreg + (size_t)l * WBLK;
        else {
            wb = Wreg;
            const size_t M2 = 512 * 512, MF1 = (size_t)512 * 2048;
            T(enc_wq + l * M2,  wb + OFF_QK,          512, 512,  0, 0, 1);
            T(enc_wk + l * M2,  wb + OFF_QK + 262144, 512, 512,  0, 0, 1);
            T(enc_wv + l * M2,  wb + OFF_WV,          512, 512,  0, 0, 1);
            T(enc_wo + l * M2,  wb + OFF_WO,          512, 512,  0, 0, 1);
            T(enc_w1 + l * MF1, wb + OFF_W1,          512, 2048, 0, 0, 1);
            T(enc_w2 + l * MF1, wb + OFF_W2,          2048, 512, 0, 0, 1);
        }
        attn(Xb, Xb, wb + OFF_QK, nullptr, wb + OFF_WV, wb + OFF_WO, T1, src, 0, true);
        add_ln_kernel<<<MTOK, 256, 0, stream>>>(X, T1, enc_ln1g + l * DDIM, enc_ln1b + l * DDIM, Xb);
        mgemm<128,128,1,1,1><<<dim3(16, 16, 1), 256, 0, stream>>>(
            Xb, 512, 0, 0, wb + OFF_W1, 512, 0, 0, HFF, FFN, 0, 0, 512, enc_b1 + l * FFN);
        mgemm<128,128,0,0,1><<<dim3(4, 16, 1), 256, 0, stream>>>(
            HFF, FFN, 0, 0, wb + OFF_W2, FFN, 0, 0, T1, 512, 0, 0, FFN, enc_b2 + l * DDIM);
        add_ln_kernel<<<MTOK, 256, 0, stream>>>(X, T1, enc_ln2g + l * DDIM, enc_ln2b + l * DDIM, Xb);
    }

    // ---- decoder ----
    embed_kernel<<<MTOK, DDIM, 0, stream>>>(trg, emb_trg, Yb, Ybf);
    for (int l = 0; l < NL; l++) {
        u16* wb;
        if (full) wb = Wreg + (size_t)(NL + l) * WBLK;
        else {
            wb = Wreg;
            const size_t M2 = 512 * 512, MF1 = (size_t)512 * 2048;
            T(dec_wq + l * M2,  wb + OFF_QK,          512, 512,  0, 0, 1);
            T(dec_wk + l * M2,  wb + OFF_QK + 262144, 512, 512,  0, 0, 1);
            T(dec_wv + l * M2,  wb + OFF_WV,          512, 512,  0, 0, 1);
            T(dec_wo + l * M2,  wb + OFF_WO,          512, 512,  0, 0, 1);
            T(dec_cq + l * M2,  wb + OFF_CQ,          512, 512,  0, 0, 1);
            T(dec_ck + l * M2,  wb + OFF_CK,          512, 512,  0, 0, 1);
            T(dec_cv + l * M2,  wb + OFF_CV,          512, 512,  0, 0, 1);
            T(dec_co + l * M2,  wb + OFF_CO,          512, 512,  0, 0, 1);
            T(dec_w1 + l * MF1, wb + OFF_W1,          512, 2048, 0, 0, 1);
            T(dec_w2 + l * MF1, wb + OFF_W2,          2048, 512, 0, 0, 1);
        }
        // masked self-attention
        attn(Ybf, Ybf, wb + OFF_QK, nullptr, wb + OFF_WV, wb + OFF_WO, T1, trg, 1, true);
        add_ln_kernel<<<MTOK, 256, 0, stream>>>(Yb, T1, dec_ln1g + l * DDIM, dec_ln1b + l * DDIM, Ybf);
        // cross-attention: Q from decoder state, K/V from encoder output
        attn(Ybf, Xb, wb + OFF_CQ, wb + OFF_CK, wb + OFF_CV, wb + OFF_CO, T1, src, 0, false);
        add_ln_kernel<<<MTOK, 256, 0, stream>>>(Yb, T1, dec_ln2g + l * DDIM, dec_ln2b + l * DDIM, Ybf);
        // FFN
        mgemm<128,128,1,1,1><<<dim3(16, 16, 1), 256, 0, stream>>>(
            Ybf, 512, 0, 0, wb + OFF_W1, 512, 0, 0, HFF, FFN, 0, 0, 512, dec_b1 + l * FFN);
        mgemm<128,128,0,0,1><<<dim3(4, 16, 1), 256, 0, stream>>>(
            HFF, FFN, 0, 0, wb + OFF_W2, FFN, 0, 0, T1, 512, 0, 0, FFN, dec_b2 + l * DDIM);
        add_ln_kernel<<<MTOK, 256, 0, stream>>>(Yb, T1, dec_ln3g + l * DDIM, dec_ln3b + l * DDIM, Ybf);
    }

    // ---- final vocab projection (proj^T overlays SCORES; all attention is done) ----
    T(proj, projT, 512, NVOC, 0, 0, 1);
    mgemm<128,128,0,0,0><<<dim3(NVOC / 128, 16, 1), 256, 0, stream>>>(
        Ybf, 512, 0, 0, projT, 512, 0, 0, OUT, NVOC, 0, 0, 512, nullptr);
}

// Round 3
// 1836.306 us; speedup vs baseline: 5.2291x; 1.5453x over previous
//
#include <hip/hip_runtime.h>
#include <math.h>

// ---------------- problem constants ----------------
#define BBATCH 4
#define SS 512
#define DDIM 512
#define FFN 2048
#define NHEAD 8
#define DHEAD 64
#define NL 6
#define NVOC 32000
#define MTOK (BBATCH*SS)       // 2048
#define PAD_ID 0

typedef unsigned short u16;
typedef __attribute__((ext_vector_type(8))) short short8;   // 8 bf16 (4 VGPRs)
typedef __attribute__((ext_vector_type(4))) float f32x4;

__device__ __forceinline__ u16 f2bf(float f) {
    union { float f; unsigned u; } v; v.f = f;
    unsigned r = ((v.u >> 16) & 1u) + 0x7fffu;   // round-to-nearest-even
    return (u16)((v.u + r) >> 16);
}

__device__ __forceinline__ void gload16(const u16* g, u16* l) {
    __builtin_amdgcn_global_load_lds(
        (const __attribute__((address_space(1))) void*)g,
        (__attribute__((address_space(3))) void*)l, 16, 0, 0);
}

// ======================= MFMA GEMM (NT): C[M,N] = A[M,K] * B[N,K]^T =======================
// A, B bf16 row-major with k contiguous; C fp32 or bf16. 256 threads = 4 waves in 2x2.
// Batched via blockIdx.z decomposed as (zb = z>>3, zh = z&7) with per-axis strides.
// LDS tiles store [row][32k] with 16B-slot XOR swizzle: phys_slot = slot ^ ((row&3)<<4).
template<int BM, int BN, int OUTBF, int RELU, int BIAS>
__global__ __launch_bounds__(256) void mgemm(
    const u16* __restrict__ A, int lda, size_t aSb, size_t aSh,
    const u16* __restrict__ B, int ldb, size_t bSb, size_t bSh,
    void* __restrict__ Cv, int ldc, size_t cSb, size_t cSh,
    int K, const float* __restrict__ bias)
{
    static_assert(BM % 64 == 0 && BN % 64 == 0, "tile");
    __shared__ __align__(16) u16 As[BM * 32];
    __shared__ __align__(16) u16 Bs[BN * 32];

    const int tid  = threadIdx.x;
    const int lane = tid & 63;
    const int wid  = tid >> 6;
    const int wr   = wid >> 1, wc = wid & 1;
    const int row0 = blockIdx.y * BM, col0 = blockIdx.x * BN;
    const int zb = blockIdx.z >> 3, zh = blockIdx.z & 7;
    A += (size_t)zb * aSb + (size_t)zh * aSh;
    B += (size_t)zb * bSb + (size_t)zh * bSh;

    constexpr int MF = BM / 32;     // m-frags per wave
    constexpr int NF = BN / 32;     // n-frags per wave
    constexpr int RA = BM / 64;     // A staging rounds (4KB each)
    constexpr int RB = BN / 64;

    const u16* aSrc[RA]; u16* aDst[RA];
    #pragma unroll
    for (int r = 0; r < RA; r++) {
        int row = (tid >> 2) + r * 64;
        int slot = ((tid & 3) << 4) ^ ((row & 3) << 4);
        aSrc[r] = A + (size_t)(row0 + row) * lda + (slot >> 1);
        aDst[r] = &As[r * 2048 + tid * 8];
    }
    const u16* bSrc[RB]; u16* bDst[RB];
    #pragma unroll
    for (int r = 0; r < RB; r++) {
        int row = (tid >> 2) + r * 64;
        int slot = ((tid & 3) << 4) ^ ((row & 3) << 4);
        bSrc[r] = B + (size_t)(col0 + row) * ldb + (slot >> 1);
        bDst[r] = &Bs[r * 2048 + tid * 8];
    }

    f32x4 acc[MF][NF];
    const f32x4 zero = {0.f, 0.f, 0.f, 0.f};
    #pragma unroll
    for (int m = 0; m < MF; m++)
        #pragma unroll
        for (int n = 0; n < NF; n++) acc[m][n] = zero;

    for (int k0 = 0; k0 < K; k0 += 32) {
        #pragma unroll
        for (int r = 0; r < RA; r++) gload16(aSrc[r] + k0, aDst[r]);
        #pragma unroll
        for (int r = 0; r < RB; r++) gload16(bSrc[r] + k0, bDst[r]);
        __syncthreads();

        short8 af[MF], bf[NF];
        #pragma unroll
        for (int m = 0; m < MF; m++) {
            int row = wr * (BM / 2) + m * 16 + (lane & 15);
            int slot = ((lane >> 4) << 4) ^ ((row & 3) << 4);
            af[m] = *(const short8*)&As[row * 32 + (slot >> 1)];
        }
        #pragma unroll
        for (int n = 0; n < NF; n++) {
            int row = wc * (BN / 2) + n * 16 + (lane & 15);
            int slot = ((lane >> 4) << 4) ^ ((row & 3) << 4);
            bf[n] = *(const short8*)&Bs[row * 32 + (slot >> 1)];
        }
        #pragma unroll
        for (int m = 0; m < MF; m++)
            #pragma unroll
            for (int n = 0; n < NF; n++)
                acc[m][n] = __builtin_amdgcn_mfma_f32_16x16x32_bf16(af[m], bf[n], acc[m][n], 0, 0, 0);
        __syncthreads();
    }

    const int crow = row0 + wr * (BM / 2);
    const int ccol = col0 + wc * (BN / 2);
    #pragma unroll
    for (int m = 0; m < MF; m++) {
        #pragma unroll
        for (int n = 0; n < NF; n++) {
            int col = ccol + n * 16 + (lane & 15);
            float bv = BIAS ? bias[col] : 0.0f;
            #pragma unroll
            for (int i = 0; i < 4; i++) {
                int row = crow + m * 16 + ((lane >> 4) << 2) + i;
                float v = acc[m][n][i] + bv;
                if (RELU) v = fmaxf(v, 0.0f);
                if (OUTBF) {
                    u16* C = (u16*)Cv + (size_t)zb * cSb + (size_t)zh * cSh;
                    C[(size_t)row * ldc + col] = f2bf(v);
                } else {
                    float* C = (float*)Cv + (size_t)zb * cSb + (size_t)zh * cSh;
                    C[(size_t)row * ldc + col] = v;
                }
            }
        }
    }
}

// ======================= fused flash attention =======================
// grid: (8 q-tiles, 32 bh).  QBLK=64 (16 q-rows per wave), KBLK=64, online softmax.
// Q from Qp[tok][ldq] cols h*64..; K from Kp[tok][ldk] cols h*64..; V^T from Vtp[512][2048]
// (row = h*64+d, col = global token).  Output CTX[tok][512] bf16.
template<int CAUSAL>
__global__ __launch_bounds__(256) void flash_attn(
    const u16* __restrict__ Qp, int ldq,
    const u16* __restrict__ Kp, int ldk,
    const u16* __restrict__ Vtp,
    u16* __restrict__ O,
    const int* __restrict__ ids)
{
    __shared__ __align__(16) u16 Kl[2][64 * 64];
    __shared__ __align__(16) u16 Vl[2][64 * 64];
    __shared__ __align__(16) u16 Pl[4][16 * 64];
    __shared__ float msk[SS];

    const int tid = threadIdx.x, lane = tid & 63, wid = tid >> 6;
    const int bh = blockIdx.y, b = bh >> 3, h = bh & 7;
    const int q0 = blockIdx.x * 64;

    // additive pad mask
    for (int i = tid; i < SS; i += 256)
        msk[i] = (ids[b * SS + i] == PAD_ID) ? -1e30f : 0.0f;

    // Q fragments held in registers for the whole block
    const int qloc = wid * 16 + (lane & 15);
    const u16* Qb = Qp + (size_t)(b * SS + q0 + qloc) * ldq + h * 64 + ((lane >> 4) * 8);
    short8 qf[2];
    qf[0] = *(const short8*)(Qb);
    qf[1] = *(const short8*)(Qb + 32);

    const u16* Kb = Kp + (size_t)b * SS * ldk + h * 64;
    const u16* Vb = Vtp + (size_t)(h * 64) * MTOK + b * SS;

    auto stage = [&](int buf, int kt) {
        int row = tid >> 3;                 // 0..31
        int sl  = tid & 7;
        #pragma unroll
        for (int r = 0; r < 2; r++) {
            int rr = row + r * 32;
            int ls = sl ^ (rr & 7);         // pre-swizzled source slot
            gload16(Kb + (size_t)(kt * 64 + rr) * ldk + ls * 8, &Kl[buf][rr * 64 + sl * 8]);
            gload16(Vb + (size_t)rr * MTOK + kt * 64 + ls * 8, &Vl[buf][rr * 64 + sl * 8]);
        }
    };

    const int nt = CAUSAL ? (blockIdx.x + 1) : (SS / 64);
    stage(0, 0);
    __syncthreads();

    float m_i[4], l_i[4];
    f32x4 o_acc[4];
    const f32x4 zero = {0.f, 0.f, 0.f, 0.f};
    #pragma unroll
    for (int i = 0; i < 4; i++) { m_i[i] = -1e30f; l_i[i] = 0.0f; }
    #pragma unroll
    for (int n = 0; n < 4; n++) o_acc[n] = zero;

    for (int kt = 0; kt < nt; kt++) {
        int cur = kt & 1;
        if (kt + 1 < nt) stage(cur ^ 1, kt + 1);

        // ---- S = Q K^T ----
        f32x4 s_acc[4];
        #pragma unroll
        for (int n = 0; n < 4; n++) s_acc[n] = zero;
        #pragma unroll
        for (int kk = 0; kk < 2; kk++) {
            #pragma unroll
            for (int n = 0; n < 4; n++) {
                int row = n * 16 + (lane & 15);
                int ls = (kk * 4 + (lane >> 4)) ^ (row & 7);
                short8 kf = *(const short8*)&Kl[cur][row * 64 + ls * 8];
                s_acc[n] = __builtin_amdgcn_mfma_f32_16x16x32_bf16(qf[kk], kf, s_acc[n], 0, 0, 0);
            }
        }

        // ---- online softmax (q = (lane>>4)*4 + i, k = n*16 + (lane&15)) ----
        float sv[4][4];
        #pragma unroll
        for (int n = 0; n < 4; n++) {
            int kg = kt * 64 + n * 16 + (lane & 15);
            float mk = msk[kg];
            #pragma unroll
            for (int i = 0; i < 4; i++) {
                float s = s_acc[n][i] * 0.125f + mk;
                if (CAUSAL) {
                    int qg = q0 + wid * 16 + ((lane >> 4) << 2) + i;
                    if (kg > qg) s = -1e30f;
                }
                sv[n][i] = s;
            }
        }
        float pm[4], mn[4], rs[4], ps[4];
        #pragma unroll
        for (int i = 0; i < 4; i++) {
            pm[i] = fmaxf(fmaxf(sv[0][i], sv[1][i]), fmaxf(sv[2][i], sv[3][i]));
        }
        #pragma unroll
        for (int i = 0; i < 4; i++) {
            #pragma unroll
            for (int msh = 1; msh <= 8; msh <<= 1)
                pm[i] = fmaxf(pm[i], __shfl_xor(pm[i], msh));
            mn[i] = fmaxf(m_i[i], pm[i]);
            rs[i] = __expf(m_i[i] - mn[i]);
            m_i[i] = mn[i];
        }
        float p[4][4];
        #pragma unroll
        for (int n = 0; n < 4; n++)
            #pragma unroll
            for (int i = 0; i < 4; i++)
                p[n][i] = (sv[n][i] < -1e29f) ? 0.0f : __expf(sv[n][i] - mn[i]);
        #pragma unroll
        for (int i = 0; i < 4; i++) {
            ps[i] = p[0][i] + p[1][i] + p[2][i] + p[3][i];
            #pragma unroll
            for (int msh = 1; msh <= 8; msh <<= 1)
                ps[i] += __shfl_xor(ps[i], msh);
            l_i[i] = l_i[i] * rs[i] + ps[i];
        }
        #pragma unroll
        for (int n = 0; n < 4; n++)
            #pragma unroll
            for (int i = 0; i < 4; i++)
                o_acc[n][i] *= rs[i];

        // ---- P -> LDS (swizzled), then PV ----
        #pragma unroll
        for (int n = 0; n < 4; n++) {
            int k = n * 16 + (lane & 15);
            #pragma unroll
            for (int i = 0; i < 4; i++) {
                int q = ((lane >> 4) << 2) + i;
                Pl[wid][q * 64 + (((k >> 3) ^ (q & 7)) << 3) + (k & 7)] = f2bf(p[n][i]);
            }
        }
        asm volatile("s_waitcnt lgkmcnt(0)" ::: "memory");

        #pragma unroll
        for (int kk = 0; kk < 2; kk++) {
            int qrow = lane & 15;
            int lsp = (kk * 4 + (lane >> 4)) ^ (qrow & 7);
            short8 pa = *(const short8*)&Pl[wid][qrow * 64 + lsp * 8];
            #pragma unroll
            for (int nf = 0; nf < 4; nf++) {
                int row = nf * 16 + (lane & 15);
                int vs = (kk * 4 + (lane >> 4)) ^ (row & 7);
                short8 vf = *(const short8*)&Vl[cur][row * 64 + vs * 8];
                o_acc[nf] = __builtin_amdgcn_mfma_f32_16x16x32_bf16(pa, vf, o_acc[nf], 0, 0, 0);
            }
        }
        __syncthreads();
    }

    // ---- epilogue ----
    #pragma unroll
    for (int nf = 0; nf < 4; nf++) {
        int d = h * 64 + nf * 16 + (lane & 15);
        #pragma unroll
        for (int i = 0; i < 4; i++) {
            int qg = b * SS + q0 + wid * 16 + ((lane >> 4) << 2) + i;
            O[(size_t)qg * DDIM + d] = f2bf(o_acc[nf][i] / l_i[i]);
        }
    }
}

// ============ weight transpose + fp32->bf16 convert:  dst[N,K] = bf16(src[K,N]) ============
__global__ __launch_bounds__(256) void transp(const float* __restrict__ src, u16* __restrict__ dst,
                                              int N, int K, size_t sStride, size_t dStride)
{
    src += (size_t)blockIdx.z * sStride;
    dst += (size_t)blockIdx.z * dStride;
    __shared__ u16 t[64][65];
    const int tid = threadIdx.x;
    const int n0 = blockIdx.x * 64, k0 = blockIdx.y * 64;
    #pragma unroll
    for (int i = 0; i < 16; i++) {
        int idx = tid + i * 256;
        int kr = idx >> 6, nc = idx & 63;
        t[kr][nc] = f2bf(src[(size_t)(k0 + kr) * N + n0 + nc]);
    }
    __syncthreads();
    #pragma unroll
    for (int i = 0; i < 16; i++) {
        int idx = tid + i * 256;
        int nr = idx >> 6, kc = idx & 63;
        dst[(size_t)(n0 + nr) * K + k0 + kc] = t[kc][nr];
    }
}

// ============ embedding + sinusoidal PE (fp32 + bf16 shadow) ============
__global__ void embed_kernel(const int* __restrict__ ids, const float* __restrict__ emb,
                             float* __restrict__ out, u16* __restrict__ outb)
{
    int tok = blockIdx.x;
    int d = threadIdx.x;
    int pos = tok & (SS - 1);
    int id = ids[tok];
    int i = d >> 1;
    double freq = exp(-(2.0 * (double)i / (double)DDIM) * log(10000.0));
    double ang = (double)pos * freq;
    float pe = (float)((d & 1) ? cos(ang) : sin(ang));
    float val = emb[(size_t)id * DDIM + d] * 22.62741699796952f + pe;
    out[(size_t)tok * DDIM + d] = val;
    outb[(size_t)tok * DDIM + d] = f2bf(val);
}

// ============ residual add + LayerNorm (fp32 in place, bf16 shadow out) ============
__global__ __launch_bounds__(256) void add_ln_kernel(float* __restrict__ x,
    const float* __restrict__ addv, const float* __restrict__ g,
    const float* __restrict__ bta, u16* __restrict__ xb)
{
    int row = blockIdx.x;
    int tid = threadIdx.x;
    size_t base = (size_t)row * DDIM;
    __shared__ float sbuf[4];

    float v0 = x[base + tid]       + addv[base + tid];
    float v1 = x[base + tid + 256] + addv[base + tid + 256];

    float s = v0 + v1;
    #pragma unroll
    for (int o = 32; o > 0; o >>= 1) s += __shfl_down(s, o);
    if ((tid & 63) == 0) sbuf[tid >> 6] = s;
    __syncthreads();
    float mean = (sbuf[0] + sbuf[1] + sbuf[2] + sbuf[3]) * (1.0f / DDIM);
    __syncthreads();

    float d0 = v0 - mean, d1 = v1 - mean;
    float ss = d0 * d0 + d1 * d1;
    #pragma unroll
    for (int o = 32; o > 0; o >>= 1) ss += __shfl_down(ss, o);
    if ((tid & 63) == 0) sbuf[tid >> 6] = ss;
    __syncthreads();
    float var = (sbuf[0] + sbuf[1] + sbuf[2] + sbuf[3]) * (1.0f / DDIM);
    float inv = rsqrtf(var + 1e-5f);

    float o0 = d0 * inv * g[tid]       + bta[tid];
    float o1 = d1 * inv * g[tid + 256] + bta[tid + 256];
    x[base + tid] = o0;
    x[base + tid + 256] = o1;
    xb[base + tid] = f2bf(o0);
    xb[base + tid + 256] = f2bf(o1);
}

// ======================= host orchestration =======================
#define OFF_QK 0u            // [1024][512]
#define OFF_WV 524288u
#define OFF_WO 786432u
#define OFF_CQ 1048576u
#define OFF_CK 1310720u
#define OFF_CV 1572864u
#define OFF_CO 1835008u
#define OFF_W1 2097152u      // [2048][512]
#define OFF_W2 3145728u      // [512][2048]
#define WBLK   4194304u

extern "C" void kernel_launch(void* const* d_in, const int* in_sizes, int n_in,
                              void* d_out, int out_size, void* d_ws, size_t ws_size,
                              hipStream_t stream)
{
    (void)in_sizes; (void)n_in; (void)out_size;

    const int*   src      = (const int*)  d_in[0];
    const int*   trg      = (const int*)  d_in[1];
    const float* emb_src  = (const float*)d_in[2];
    const float* emb_trg  = (const float*)d_in[3];
    const float* enc_wq   = (const float*)d_in[4];
    const float* enc_wk   = (const float*)d_in[5];
    const float* enc_wv   = (const float*)d_in[6];
    const float* enc_wo   = (const float*)d_in[7];
    const float* enc_ln1g = (const float*)d_in[8];
    const float* enc_ln1b = (const float*)d_in[9];
    const float* enc_w1   = (const float*)d_in[10];
    const float* enc_b1   = (const float*)d_in[11];
    const float* enc_w2   = (const float*)d_in[12];
    const float* enc_b2   = (const float*)d_in[13];
    const float* enc_ln2g = (const float*)d_in[14];
    const float* enc_ln2b = (const float*)d_in[15];
    const float* dec_wq   = (const float*)d_in[16];
    const float* dec_wk   = (const float*)d_in[17];
    const float* dec_wv   = (const float*)d_in[18];
    const float* dec_wo   = (const float*)d_in[19];
    const float* dec_ln1g = (const float*)d_in[20];
    const float* dec_ln1b = (const float*)d_in[21];
    const float* dec_cq   = (const float*)d_in[22];
    const float* dec_ck   = (const float*)d_in[23];
    const float* dec_cv   = (const float*)d_in[24];
    const float* dec_co   = (const float*)d_in[25];
    const float* dec_ln2g = (const float*)d_in[26];
    const float* dec_ln2b = (const float*)d_in[27];
    const float* dec_w1   = (const float*)d_in[28];
    const float* dec_b1   = (const float*)d_in[29];
    const float* dec_w2   = (const float*)d_in[30];
    const float* dec_b2   = (const float*)d_in[31];
    const float* dec_ln3g = (const float*)d_in[32];
    const float* dec_ln3b = (const float*)d_in[33];
    const float* proj     = (const float*)d_in[34];

    float* OUT = (float*)d_out;
    char* base = (char*)d_ws;

    const size_t MSZ = (size_t)MTOK * DDIM;
    size_t off = 0;
    auto carve = [&](size_t bytes) { char* p = base + off; off += (bytes + 255) & ~(size_t)255; return p; };

    float* X      = (float*)carve(MSZ * 4);
    float* Yb     = (float*)carve(MSZ * 4);
    float* T1     = (float*)carve(MSZ * 4);
    u16*   Xb     = (u16*)  carve(MSZ * 2);
    u16*   Ybf    = (u16*)  carve(MSZ * 2);
    u16*   QKb    = (u16*)  carve((size_t)MTOK * 1024 * 2);      // Q|K packed, ld 1024
    u16*   Vt     = (u16*)  carve((size_t)512 * MTOK * 2);       // V^T [512][2048]
    u16*   CTX    = (u16*)  carve(MSZ * 2);
    u16*   HFF    = (u16*)  carve((size_t)MTOK * FFN * 2);
    u16*   Kcr    = (u16*)  carve((size_t)NL * MTOK * 512 * 2);  // cross K per layer
    u16*   Vtc    = (u16*)  carve((size_t)NL * 512 * MTOK * 2);  // cross V^T per layer
    u16*   projT  = (u16*)  carve((size_t)NVOC * 512 * 2);

    const size_t WFULL_B = (size_t)12 * WBLK * 2;
    bool full = (ws_size >= off + WFULL_B);
    u16* Wreg = (u16*)carve(full ? WFULL_B : (size_t)WBLK * 2);

    auto T = [&](const float* s, u16* d, int Kd, int Nd, size_t ss, size_t ds, int L) {
        transp<<<dim3(Nd / 64, Kd / 64, L), 256, 0, stream>>>(s, d, Nd, Kd, ss, ds);
    };

    const size_t M2 = 512 * 512, MF1 = (size_t)512 * 2048;
    if (full) {
        T(enc_wq, Wreg + OFF_QK,          512, 512,  M2, WBLK, NL);
        T(enc_wk, Wreg + OFF_QK + 262144, 512, 512,  M2, WBLK, NL);
        T(enc_wv, Wreg + OFF_WV,          512, 512,  M2, WBLK, NL);
        T(enc_wo, Wreg + OFF_WO,          512, 512,  M2, WBLK, NL);
        T(enc_w1, Wreg + OFF_W1,          512, 2048, MF1, WBLK, NL);
        T(enc_w2, Wreg + OFF_W2,          2048, 512, MF1, WBLK, NL);
        u16* Wd = Wreg + (size_t)NL * WBLK;
        T(dec_wq, Wd + OFF_QK,          512, 512,  M2, WBLK, NL);
        T(dec_wk, Wd + OFF_QK + 262144, 512, 512,  M2, WBLK, NL);
        T(dec_wv, Wd + OFF_WV,          512, 512,  M2, WBLK, NL);
        T(dec_wo, Wd + OFF_WO,          512, 512,  M2, WBLK, NL);
        T(dec_cq, Wd + OFF_CQ,          512, 512,  M2, WBLK, NL);
        T(dec_ck, Wd + OFF_CK,          512, 512,  M2, WBLK, NL);
        T(dec_cv, Wd + OFF_CV,          512, 512,  M2, WBLK, NL);
        T(dec_co, Wd + OFF_CO,          512, 512,  M2, WBLK, NL);
        T(dec_w1, Wd + OFF_W1,          512, 2048, MF1, WBLK, NL);
        T(dec_w2, Wd + OFF_W2,          2048, 512, MF1, WBLK, NL);
    }

    // self-attention block (QK fused GEMM + Vt GEMM + flash + O-proj -> T1)
    auto self_attn = [&](const u16* xsrc, const u16* wb, const int* mask_ids, int causal) {
        // Q|K: [2048][1024]
        mgemm<64,128,1,0,0><<<dim3(8, 32, 1), 256, 0, stream>>>(
            xsrc, 512, 0, 0, wb + OFF_QK, 512, 0, 0, QKb, 1024, 0, 0, 512, nullptr);
        // V^T[512][2048]
        mgemm<64,128,1,0,0><<<dim3(16, 8, 1), 256, 0, stream>>>(
            wb + OFF_WV, 512, 0, 0, xsrc, 512, 0, 0, Vt, MTOK, 0, 0, 512, nullptr);
        if (causal)
            flash_attn<1><<<dim3(8, 32), 256, 0, stream>>>(QKb, 1024, QKb + 512, 1024, Vt, CTX, mask_ids);
        else
            flash_attn<0><<<dim3(8, 32), 256, 0, stream>>>(QKb, 1024, QKb + 512, 1024, Vt, CTX, mask_ids);
        mgemm<64,64,0,0,0><<<dim3(8, 32, 1), 256, 0, stream>>>(
            CTX, 512, 0, 0, wb + OFF_WO, 512, 0, 0, T1, 512, 0, 0, 512, nullptr);
    };

    // ---- encoder ----
    embed_kernel<<<MTOK, DDIM, 0, stream>>>(src, emb_src, X, Xb);
    for (int l = 0; l < NL; l++) {
        u16* wb;
        if (full) wb = Wreg + (size_t)l * WBLK;
        else {
            wb = Wreg;
            T(enc_wq + l * M2,  wb + OFF_QK,          512, 512,  0, 0, 1);
            T(enc_wk + l * M2,  wb + OFF_QK + 262144, 512, 512,  0, 0, 1);
            T(enc_wv + l * M2,  wb + OFF_WV,          512, 512,  0, 0, 1);
            T(enc_wo + l * M2,  wb + OFF_WO,          512, 512,  0, 0, 1);
            T(enc_w1 + l * MF1, wb + OFF_W1,          512, 2048, 0, 0, 1);
            T(enc_w2 + l * MF1, wb + OFF_W2,          2048, 512, 0, 0, 1);
        }
        self_attn(Xb, wb, src, 0);
        add_ln_kernel<<<MTOK, 256, 0, stream>>>(X, T1, enc_ln1g + l * DDIM, enc_ln1b + l * DDIM, Xb);
        mgemm<128,128,1,1,1><<<dim3(16, 16, 1), 256, 0, stream>>>(
            Xb, 512, 0, 0, wb + OFF_W1, 512, 0, 0, HFF, FFN, 0, 0, 512, enc_b1 + l * FFN);
        mgemm<64,64,0,0,1><<<dim3(8, 32, 1), 256, 0, stream>>>(
            HFF, FFN, 0, 0, wb + OFF_W2, FFN, 0, 0, T1, 512, 0, 0, FFN, enc_b2 + l * DDIM);
        add_ln_kernel<<<MTOK, 256, 0, stream>>>(X, T1, enc_ln2g + l * DDIM, enc_ln2b + l * DDIM, Xb);
    }

    // ---- cross-attention K / V^T for all 6 decoder layers (batched over z) ----
    if (full) {
        u16* Wd = Wreg + (size_t)NL * WBLK;
        mgemm<128,128,1,0,0><<<dim3(4, 16, NL), 256, 0, stream>>>(
            Xb, 512, 0, 0, Wd + OFF_CK, 512, 0, WBLK, Kcr, 512, 0, (size_t)MTOK * 512, 512, nullptr);
        mgemm<128,128,1,0,0><<<dim3(16, 4, NL), 256, 0, stream>>>(
            Wd + OFF_CV, 512, 0, WBLK, Xb, 512, 0, 0, Vtc, MTOK, 0, (size_t)512 * MTOK, 512, nullptr);
    }

    // ---- decoder ----
    embed_kernel<<<MTOK, DDIM, 0, stream>>>(trg, emb_trg, Yb, Ybf);
    for (int l = 0; l < NL; l++) {
        u16* wb;
        if (full) wb = Wreg + (size_t)(NL + l) * WBLK;
        else {
            wb = Wreg;
            T(dec_wq + l * M2,  wb + OFF_QK,          512, 512,  0, 0, 1);
            T(dec_wk + l * M2,  wb + OFF_QK + 262144, 512, 512,  0, 0, 1);
            T(dec_wv + l * M2,  wb + OFF_WV,          512, 512,  0, 0, 1);
            T(dec_wo + l * M2,  wb + OFF_WO,          512, 512,  0, 0, 1);
            T(dec_cq + l * M2,  wb + OFF_CQ,          512, 512,  0, 0, 1);
            T(dec_ck + l * M2,  wb + OFF_CK,          512, 512,  0, 0, 1);
            T(dec_cv + l * M2,  wb + OFF_CV,          512, 512,  0, 0, 1);
            T(dec_co + l * M2,  wb + OFF_CO,          512, 512,  0, 0, 1);
            T(dec_w1 + l * MF1, wb + OFF_W1,          512, 2048, 0, 0, 1);
            T(dec_w2 + l * MF1, wb + OFF_W2,          2048, 512, 0, 0, 1);
            mgemm<128,128,1,0,0><<<dim3(4, 16, 1), 256, 0, stream>>>(
                Xb, 512, 0, 0, wb + OFF_CK, 512, 0, 0, Kcr + (size_t)l * MTOK * 512, 512, 0, 0, 512, nullptr);
            mgemm<128,128,1,0,0><<<dim3(16, 4, 1), 256, 0, stream>>>(
                wb + OFF_CV, 512, 0, 0, Xb, 512, 0, 0, Vtc + (size_t)l * 512 * MTOK, MTOK, 0, 0, 512, nullptr);
        }
        // masked self-attention
        self_attn(Ybf, wb, trg, 1);
        add_ln_kernel<<<MTOK, 256, 0, stream>>>(Yb, T1, dec_ln1g + l * DDIM, dec_ln1b + l * DDIM, Ybf);
        // cross-attention
        mgemm<64,64,1,0,0><<<dim3(8, 32, 1), 256, 0, stream>>>(
            Ybf, 512, 0, 0, wb + OFF_CQ, 512, 0, 0, QKb, 1024, 0, 0, 512, nullptr);
        flash_attn<0><<<dim3(8, 32), 256, 0, stream>>>(
            QKb, 1024, Kcr + (size_t)l * MTOK * 512, 512, Vtc + (size_t)l * 512 * MTOK, CTX, src);
        mgemm<64,64,0,0,0><<<dim3(8, 32, 1), 256, 0, stream>>>(
            CTX, 512, 0, 0, wb + OFF_CO, 512, 0, 0, T1, 512, 0, 0, 512, nullptr);
        add_ln_kernel<<<MTOK, 256, 0, stream>>>(Yb, T1, dec_ln2g + l * DDIM, dec_ln2b + l * DDIM, Ybf);
        // FFN
        mgemm<128,128,1,1,1><<<dim3(16, 16, 1), 256, 0, stream>>>(
            Ybf, 512, 0, 0, wb + OFF_W1, 512, 0, 0, HFF, FFN, 0, 0, 512, dec_b1 + l * FFN);
        mgemm<64,64,0,0,1><<<dim3(8, 32, 1), 256, 0, stream>>>(
            HFF, FFN, 0, 0, wb + OFF_W2, FFN, 0, 0, T1, 512, 0, 0, FFN, dec_b2 + l * DDIM);
        add_ln_kernel<<<MTOK, 256, 0, stream>>>(Yb, T1, dec_ln3g + l * DDIM, dec_ln3b + l * DDIM, Ybf);
    }

    // ---- final vocab projection ----
    T(proj, projT, 512, NVOC, 0, 0, 1);
    mgemm<128,128,0,0,0><<<dim3(NVOC / 128, 16, 1), 256, 0, stream>>>(
        Ybf, 512, 0, 0, projT, 512, 0, 0, OUT, NVOC, 0, 0, 512, nullptr);
}

// Round 4
// 1586.542 us; speedup vs baseline: 6.0523x; 1.1574x over previous
//
#include <hip/hip_runtime.h>
#include <math.h>

// ---------------- problem constants ----------------
#define BBATCH 4
#define SS 512
#define DDIM 512
#define FFN 2048
#define NHEAD 8
#define DHEAD 64
#define NL 6
#define NVOC 32000
#define MTOK (BBATCH*SS)       // 2048
#define PAD_ID 0

typedef unsigned short u16;
typedef __attribute__((ext_vector_type(8))) short short8;   // 8 bf16 (4 VGPRs)
typedef __attribute__((ext_vector_type(4))) float f32x4;

__device__ __forceinline__ u16 f2bf(float f) {
    union { float f; unsigned u; } v; v.f = f;
    unsigned r = ((v.u >> 16) & 1u) + 0x7fffu;   // round-to-nearest-even
    return (u16)((v.u + r) >> 16);
}

__device__ __forceinline__ void gload16(const u16* g, u16* l) {
    __builtin_amdgcn_global_load_lds(
        (const __attribute__((address_space(1))) void*)g,
        (__attribute__((address_space(3))) void*)l, 16, 0, 0);
}

// ======================= MFMA GEMM core (NT): C[M,N] = A[M,K] * B[N,K]^T =======================
// Double-buffered LDS (minimum 2-phase pipeline): stage tile t+1 while computing tile t.
// LDS tiles [row][32k] with 16B-slot XOR swizzle: phys_slot = slot ^ ((row&3)<<4).
template<int BM, int BN, int OUTBF, int RELU, int BIAS>
__device__ __forceinline__ void gemm_core(
    u16* __restrict__ AsB, u16* __restrict__ BsB,
    const u16* __restrict__ A, int lda,
    const u16* __restrict__ B, int ldb,
    void* __restrict__ Cv, int ldc,
    int row0, int col0, int K, const float* __restrict__ bias)
{
    const int tid  = threadIdx.x;
    const int lane = tid & 63;
    const int wid  = tid >> 6;
    const int wr   = wid >> 1, wc = wid & 1;
    constexpr int MF = BM / 32, NF = BN / 32, RA = BM / 64, RB = BN / 64;

    const u16* aSrc[RA]; int aOff[RA];
    #pragma unroll
    for (int r = 0; r < RA; r++) {
        int row = (tid >> 2) + r * 64;
        int slot = ((tid & 3) << 4) ^ ((row & 3) << 4);
        aSrc[r] = A + (size_t)(row0 + row) * lda + (slot >> 1);
        aOff[r] = r * 2048 + tid * 8;
    }
    const u16* bSrc[RB]; int bOff[RB];
    #pragma unroll
    for (int r = 0; r < RB; r++) {
        int row = (tid >> 2) + r * 64;
        int slot = ((tid & 3) << 4) ^ ((row & 3) << 4);
        bSrc[r] = B + (size_t)(col0 + row) * ldb + (slot >> 1);
        bOff[r] = r * 2048 + tid * 8;
    }

    f32x4 acc[MF][NF];
    const f32x4 zero = {0.f, 0.f, 0.f, 0.f};
    #pragma unroll
    for (int m = 0; m < MF; m++)
        #pragma unroll
        for (int n = 0; n < NF; n++) acc[m][n] = zero;

    const int nt = K / 32;
    // prologue: stage tile 0 into buffer 0
    #pragma unroll
    for (int r = 0; r < RA; r++) gload16(aSrc[r], AsB + aOff[r]);
    #pragma unroll
    for (int r = 0; r < RB; r++) gload16(bSrc[r], BsB + bOff[r]);
    __syncthreads();

    for (int t = 0; t < nt; t++) {
        const int cur = t & 1;
        if (t + 1 < nt) {   // prefetch next tile into alternate buffer
            u16* ad = AsB + (cur ^ 1) * (BM * 32);
            u16* bd = BsB + (cur ^ 1) * (BN * 32);
            #pragma unroll
            for (int r = 0; r < RA; r++) gload16(aSrc[r] + (t + 1) * 32, ad + aOff[r]);
            #pragma unroll
            for (int r = 0; r < RB; r++) gload16(bSrc[r] + (t + 1) * 32, bd + bOff[r]);
        }
        const u16* as = AsB + cur * (BM * 32);
        const u16* bs = BsB + cur * (BN * 32);
        short8 af[MF], bf[NF];
        #pragma unroll
        for (int m = 0; m < MF; m++) {
            int row = wr * (BM / 2) + m * 16 + (lane & 15);
            int slot = ((lane >> 4) << 4) ^ ((row & 3) << 4);
            af[m] = *(const short8*)&as[row * 32 + (slot >> 1)];
        }
        #pragma unroll
        for (int n = 0; n < NF; n++) {
            int row = wc * (BN / 2) + n * 16 + (lane & 15);
            int slot = ((lane >> 4) << 4) ^ ((row & 3) << 4);
            bf[n] = *(const short8*)&bs[row * 32 + (slot >> 1)];
        }
        #pragma unroll
        for (int m = 0; m < MF; m++)
            #pragma unroll
            for (int n = 0; n < NF; n++)
                acc[m][n] = __builtin_amdgcn_mfma_f32_16x16x32_bf16(af[m], bf[n], acc[m][n], 0, 0, 0);
        __syncthreads();
    }

    const int crow = row0 + wr * (BM / 2);
    const int ccol = col0 + wc * (BN / 2);
    #pragma unroll
    for (int m = 0; m < MF; m++) {
        #pragma unroll
        for (int n = 0; n < NF; n++) {
            int col = ccol + n * 16 + (lane & 15);
            float bv = BIAS ? bias[col] : 0.0f;
            #pragma unroll
            for (int i = 0; i < 4; i++) {
                int row = crow + m * 16 + ((lane >> 4) << 2) + i;
                float v = acc[m][n][i] + bv;
                if (RELU) v = fmaxf(v, 0.0f);
                if (OUTBF) ((u16*)Cv)[(size_t)row * ldc + col] = f2bf(v);
                else       ((float*)Cv)[(size_t)row * ldc + col] = v;
            }
        }
    }
}

// batched/swizzled wrapper
template<int BM, int BN, int OUTBF, int RELU, int BIAS, int SWZ = 0>
__global__ __launch_bounds__(256) void mgemm(
    const u16* __restrict__ A, int lda, size_t aSb, size_t aSh,
    const u16* __restrict__ B, int ldb, size_t bSb, size_t bSh,
    void* __restrict__ Cv, int ldc, size_t cSb, size_t cSh,
    int K, const float* __restrict__ bias)
{
    __shared__ __align__(16) u16 As[2 * BM * 32];
    __shared__ __align__(16) u16 Bs[2 * BN * 32];
    int bx = blockIdx.x, by = blockIdx.y;
    if (SWZ) {   // XCD-aware bijective remap (requires nwg % 8 == 0)
        int nwg = gridDim.x * gridDim.y;
        int lin = by * gridDim.x + bx;
        int cpx = nwg >> 3;
        int s = (lin & 7) * cpx + (lin >> 3);
        bx = s % gridDim.x; by = s / gridDim.x;
    }
    const int zb = blockIdx.z >> 3, zh = blockIdx.z & 7;
    const u16* Ab = A + (size_t)zb * aSb + (size_t)zh * aSh;
    const u16* Bb = B + (size_t)zb * bSb + (size_t)zh * bSh;
    void* Cb = OUTBF ? (void*)((u16*)Cv + (size_t)zb * cSb + (size_t)zh * cSh)
                     : (void*)((float*)Cv + (size_t)zb * cSb + (size_t)zh * cSh);
    gemm_core<BM, BN, OUTBF, RELU, BIAS>(As, Bs, Ab, lda, Bb, ldb, Cb, ldc,
                                          by * BM, bx * BN, K, bias);
}

// dual-job GEMM: two independent NT gemms (same tile config, bf16 out, no bias) in one launch
template<int BM, int BN>
__global__ __launch_bounds__(256) void mgemm_dual(
    const u16* __restrict__ A1, int lda1, const u16* __restrict__ B1, int ldb1,
    u16* __restrict__ C1, int ldc1, int nx1, int nblk1,
    const u16* __restrict__ A2, int lda2, const u16* __restrict__ B2, int ldb2,
    u16* __restrict__ C2, int ldc2, int nx2,
    int K)
{
    __shared__ __align__(16) u16 As[2 * BM * 32];
    __shared__ __align__(16) u16 Bs[2 * BN * 32];
    int id = blockIdx.x;
    if (id < nblk1) {
        gemm_core<BM, BN, 1, 0, 0>(As, Bs, A1, lda1, B1, ldb1, C1, ldc1,
                                    (id / nx1) * BM, (id % nx1) * BN, K, nullptr);
    } else {
        id -= nblk1;
        gemm_core<BM, BN, 1, 0, 0>(As, Bs, A2, lda2, B2, ldb2, C2, ldc2,
                                    (id / nx2) * BM, (id % nx2) * BN, K, nullptr);
    }
}

// ======================= fused flash attention =======================
template<int CAUSAL>
__global__ __launch_bounds__(256) void flash_attn(
    const u16* __restrict__ Qp, int ldq,
    const u16* __restrict__ Kp, int ldk,
    const u16* __restrict__ Vtp,
    u16* __restrict__ O,
    const int* __restrict__ ids)
{
    __shared__ __align__(16) u16 Kl[2][64 * 64];
    __shared__ __align__(16) u16 Vl[2][64 * 64];
    __shared__ __align__(16) u16 Pl[4][16 * 64];
    __shared__ float msk[SS];

    const int tid = threadIdx.x, lane = tid & 63, wid = tid >> 6;
    const int bh = blockIdx.y, b = bh >> 3, h = bh & 7;
    const int q0 = blockIdx.x * 64;

    for (int i = tid; i < SS; i += 256)
        msk[i] = (ids[b * SS + i] == PAD_ID) ? -1e30f : 0.0f;

    const int qloc = wid * 16 + (lane & 15);
    const u16* Qb = Qp + (size_t)(b * SS + q0 + qloc) * ldq + h * 64 + ((lane >> 4) * 8);
    short8 qf[2];
    qf[0] = *(const short8*)(Qb);
    qf[1] = *(const short8*)(Qb + 32);

    const u16* Kb = Kp + (size_t)b * SS * ldk + h * 64;
    const u16* Vb = Vtp + (size_t)(h * 64) * MTOK + b * SS;

    auto stage = [&](int buf, int kt) {
        int row = tid >> 3;
        int sl  = tid & 7;
        #pragma unroll
        for (int r = 0; r < 2; r++) {
            int rr = row + r * 32;
            int ls = sl ^ (rr & 7);
            gload16(Kb + (size_t)(kt * 64 + rr) * ldk + ls * 8, &Kl[buf][rr * 64 + sl * 8]);
            gload16(Vb + (size_t)rr * MTOK + kt * 64 + ls * 8, &Vl[buf][rr * 64 + sl * 8]);
        }
    };

    const int nt = CAUSAL ? (blockIdx.x + 1) : (SS / 64);
    stage(0, 0);
    __syncthreads();

    float m_i[4], l_i[4];
    f32x4 o_acc[4];
    const f32x4 zero = {0.f, 0.f, 0.f, 0.f};
    #pragma unroll
    for (int i = 0; i < 4; i++) { m_i[i] = -1e30f; l_i[i] = 0.0f; }
    #pragma unroll
    for (int n = 0; n < 4; n++) o_acc[n] = zero;

    for (int kt = 0; kt < nt; kt++) {
        int cur = kt & 1;
        if (kt + 1 < nt) stage(cur ^ 1, kt + 1);

        f32x4 s_acc[4];
        #pragma unroll
        for (int n = 0; n < 4; n++) s_acc[n] = zero;
        #pragma unroll
        for (int kk = 0; kk < 2; kk++) {
            #pragma unroll
            for (int n = 0; n < 4; n++) {
                int row = n * 16 + (lane & 15);
                int ls = (kk * 4 + (lane >> 4)) ^ (row & 7);
                short8 kf = *(const short8*)&Kl[cur][row * 64 + ls * 8];
                s_acc[n] = __builtin_amdgcn_mfma_f32_16x16x32_bf16(qf[kk], kf, s_acc[n], 0, 0, 0);
            }
        }

        float sv[4][4];
        #pragma unroll
        for (int n = 0; n < 4; n++) {
            int kg = kt * 64 + n * 16 + (lane & 15);
            float mk = msk[kg];
            #pragma unroll
            for (int i = 0; i < 4; i++) {
                float s = s_acc[n][i] * 0.125f + mk;
                if (CAUSAL) {
                    int qg = q0 + wid * 16 + ((lane >> 4) << 2) + i;
                    if (kg > qg) s = -1e30f;
                }
                sv[n][i] = s;
            }
        }
        float pm[4], mn[4], rs[4], ps[4];
        #pragma unroll
        for (int i = 0; i < 4; i++)
            pm[i] = fmaxf(fmaxf(sv[0][i], sv[1][i]), fmaxf(sv[2][i], sv[3][i]));
        #pragma unroll
        for (int i = 0; i < 4; i++) {
            #pragma unroll
            for (int msh = 1; msh <= 8; msh <<= 1)
                pm[i] = fmaxf(pm[i], __shfl_xor(pm[i], msh));
            mn[i] = fmaxf(m_i[i], pm[i]);
            rs[i] = __expf(m_i[i] - mn[i]);
            m_i[i] = mn[i];
        }
        float p[4][4];
        #pragma unroll
        for (int n = 0; n < 4; n++)
            #pragma unroll
            for (int i = 0; i < 4; i++)
                p[n][i] = (sv[n][i] < -1e29f) ? 0.0f : __expf(sv[n][i] - mn[i]);
        #pragma unroll
        for (int i = 0; i < 4; i++) {
            ps[i] = p[0][i] + p[1][i] + p[2][i] + p[3][i];
            #pragma unroll
            for (int msh = 1; msh <= 8; msh <<= 1)
                ps[i] += __shfl_xor(ps[i], msh);
            l_i[i] = l_i[i] * rs[i] + ps[i];
        }
        #pragma unroll
        for (int n = 0; n < 4; n++)
            #pragma unroll
            for (int i = 0; i < 4; i++)
                o_acc[n][i] *= rs[i];

        #pragma unroll
        for (int n = 0; n < 4; n++) {
            int k = n * 16 + (lane & 15);
            #pragma unroll
            for (int i = 0; i < 4; i++) {
                int q = ((lane >> 4) << 2) + i;
                Pl[wid][q * 64 + (((k >> 3) ^ (q & 7)) << 3) + (k & 7)] = f2bf(p[n][i]);
            }
        }
        asm volatile("s_waitcnt lgkmcnt(0)" ::: "memory");

        #pragma unroll
        for (int kk = 0; kk < 2; kk++) {
            int qrow = lane & 15;
            int lsp = (kk * 4 + (lane >> 4)) ^ (qrow & 7);
            short8 pa = *(const short8*)&Pl[wid][qrow * 64 + lsp * 8];
            #pragma unroll
            for (int nf = 0; nf < 4; nf++) {
                int row = nf * 16 + (lane & 15);
                int vs = (kk * 4 + (lane >> 4)) ^ (row & 7);
                short8 vf = *(const short8*)&Vl[cur][row * 64 + vs * 8];
                o_acc[nf] = __builtin_amdgcn_mfma_f32_16x16x32_bf16(pa, vf, o_acc[nf], 0, 0, 0);
            }
        }
        __syncthreads();
    }

    #pragma unroll
    for (int nf = 0; nf < 4; nf++) {
        int d = h * 64 + nf * 16 + (lane & 15);
        #pragma unroll
        for (int i = 0; i < 4; i++) {
            int qg = b * SS + q0 + wid * 16 + ((lane >> 4) << 2) + i;
            O[(size_t)qg * DDIM + d] = f2bf(o_acc[nf][i] / l_i[i]);
        }
    }
}

// ============ transpose + convert core: dst[N,K] = bf16(src[K,N]) (64x64 tile) ============
__device__ __forceinline__ void transp_core(const float* __restrict__ src, u16* __restrict__ dst,
                                            int N, int K, int n0, int k0)
{
    __shared__ u16 t[64][65];
    const int tid = threadIdx.x;
    #pragma unroll
    for (int i = 0; i < 16; i++) {
        int idx = tid + i * 256;
        int kr = idx >> 6, nc = idx & 63;
        t[kr][nc] = f2bf(src[(size_t)(k0 + kr) * N + n0 + nc]);
    }
    __syncthreads();
    #pragma unroll
    for (int i = 0; i < 16; i++) {
        int idx = tid + i * 256;
        int nr = idx >> 6, kc = idx & 63;
        dst[(size_t)(n0 + nr) * K + k0 + kc] = t[kc][nr];
    }
}

__global__ __launch_bounds__(256) void transp(const float* __restrict__ src, u16* __restrict__ dst,
                                              int N, int K, size_t sStride, size_t dStride)
{
    transp_core(src + (size_t)blockIdx.z * sStride, dst + (size_t)blockIdx.z * dStride,
                N, K, blockIdx.x * 64, blockIdx.y * 64);
}

// ---- weight-block layout (u16 offsets) ----
#define OFF_QK 0u            // [1024][512]
#define OFF_WV 524288u
#define OFF_WO 786432u
#define OFF_CQ 1048576u
#define OFF_CK 1310720u
#define OFF_CV 1572864u
#define OFF_CO 1835008u
#define OFF_W1 2097152u      // [2048][512]
#define OFF_W2 3145728u      // [512][2048]
#define WBLK   4194304u
#define M2CNT  262144u
#define MF1CNT 1048576u

// all 12 square (512x512) attention weights, batched: z = l*12 + w
__global__ __launch_bounds__(256) void transpW(
    const float* p0, const float* p1, const float* p2, const float* p3,
    const float* p4, const float* p5, const float* p6, const float* p7,
    const float* p8, const float* p9, const float* p10, const float* p11,
    u16* __restrict__ wreg)
{
    int z = blockIdx.z;
    int w = z % 12, l = z / 12;
    const float* ptrs[12] = {p0,p1,p2,p3,p4,p5,p6,p7,p8,p9,p10,p11};
    const float* src = ptrs[w] + (size_t)l * M2CNT;
    u16* dst = wreg + (w < 4 ? (size_t)l * WBLK + (size_t)w * M2CNT
                             : (size_t)(NL + l) * WBLK + (size_t)(w - 4) * M2CNT);
    transp_core(src, dst, 512, 512, blockIdx.x * 64, blockIdx.y * 64);
}

// enc_w1 + dec_w1 (512->2048): z = w*NL + l
__global__ __launch_bounds__(256) void transpF1(const float* __restrict__ e,
                                                const float* __restrict__ d, u16* __restrict__ wreg)
{
    int z = blockIdx.z; int l = z % NL, w = z / NL;
    const float* src = (w ? d : e) + (size_t)l * MF1CNT;
    u16* dst = wreg + (size_t)(w * NL + l) * WBLK + OFF_W1;
    transp_core(src, dst, 2048, 512, blockIdx.x * 64, blockIdx.y * 64);
}

// enc_w2 + dec_w2 (2048->512)
__global__ __launch_bounds__(256) void transpF2(const float* __restrict__ e,
                                                const float* __restrict__ d, u16* __restrict__ wreg)
{
    int z = blockIdx.z; int l = z % NL, w = z / NL;
    const float* src = (w ? d : e) + (size_t)l * MF1CNT;
    u16* dst = wreg + (size_t)(w * NL + l) * WBLK + OFF_W2;
    transp_core(src, dst, 512, 2048, blockIdx.x * 64, blockIdx.y * 64);
}

// ============ positional-encoding table (fp64, once) ============
__global__ void pe_kernel(float* __restrict__ PEt)
{
    int pos = blockIdx.x, d = threadIdx.x;
    int i = d >> 1;
    double freq = exp(-(2.0 * (double)i / (double)DDIM) * log(10000.0));
    double ang = (double)pos * freq;
    PEt[pos * DDIM + d] = (float)((d & 1) ? cos(ang) : sin(ang));
}

// ============ embedding + PE (fp32 + bf16 shadow) ============
__global__ void embed_kernel(const int* __restrict__ ids, const float* __restrict__ emb,
                             const float* __restrict__ PEt,
                             float* __restrict__ out, u16* __restrict__ outb)
{
    int tok = blockIdx.x;
    int d = threadIdx.x;
    int pos = tok & (SS - 1);
    int id = ids[tok];
    float val = emb[(size_t)id * DDIM + d] * 22.62741699796952f + PEt[pos * DDIM + d];
    out[(size_t)tok * DDIM + d] = val;
    outb[(size_t)tok * DDIM + d] = f2bf(val);
}

// ============ residual add + LayerNorm (fp32 in place, bf16 shadow out) ============
__global__ __launch_bounds__(256) void add_ln_kernel(float* __restrict__ x,
    const float* __restrict__ addv, const float* __restrict__ g,
    const float* __restrict__ bta, u16* __restrict__ xb)
{
    int row = blockIdx.x;
    int tid = threadIdx.x;
    size_t base = (size_t)row * DDIM;
    __shared__ float sbuf[4];

    float v0 = x[base + tid]       + addv[base + tid];
    float v1 = x[base + tid + 256] + addv[base + tid + 256];

    float s = v0 + v1;
    #pragma unroll
    for (int o = 32; o > 0; o >>= 1) s += __shfl_down(s, o);
    if ((tid & 63) == 0) sbuf[tid >> 6] = s;
    __syncthreads();
    float mean = (sbuf[0] + sbuf[1] + sbuf[2] + sbuf[3]) * (1.0f / DDIM);
    __syncthreads();

    float d0 = v0 - mean, d1 = v1 - mean;
    float ss = d0 * d0 + d1 * d1;
    #pragma unroll
    for (int o = 32; o > 0; o >>= 1) ss += __shfl_down(ss, o);
    if ((tid & 63) == 0) sbuf[tid >> 6] = ss;
    __syncthreads();
    float var = (sbuf[0] + sbuf[1] + sbuf[2] + sbuf[3]) * (1.0f / DDIM);
    float inv = rsqrtf(var + 1e-5f);

    float o0 = d0 * inv * g[tid]       + bta[tid];
    float o1 = d1 * inv * g[tid + 256] + bta[tid + 256];
    x[base + tid] = o0;
    x[base + tid + 256] = o1;
    xb[base + tid] = f2bf(o0);
    xb[base + tid + 256] = f2bf(o1);
}

// ======================= host orchestration =======================
extern "C" void kernel_launch(void* const* d_in, const int* in_sizes, int n_in,
                              void* d_out, int out_size, void* d_ws, size_t ws_size,
                              hipStream_t stream)
{
    (void)in_sizes; (void)n_in; (void)out_size;

    const int*   src      = (const int*)  d_in[0];
    const int*   trg      = (const int*)  d_in[1];
    const float* emb_src  = (const float*)d_in[2];
    const float* emb_trg  = (const float*)d_in[3];
    const float* enc_wq   = (const float*)d_in[4];
    const float* enc_wk   = (const float*)d_in[5];
    const float* enc_wv   = (const float*)d_in[6];
    const float* enc_wo   = (const float*)d_in[7];
    const float* enc_ln1g = (const float*)d_in[8];
    const float* enc_ln1b = (const float*)d_in[9];
    const float* enc_w1   = (const float*)d_in[10];
    const float* enc_b1   = (const float*)d_in[11];
    const float* enc_w2   = (const float*)d_in[12];
    const float* enc_b2   = (const float*)d_in[13];
    const float* enc_ln2g = (const float*)d_in[14];
    const float* enc_ln2b = (const float*)d_in[15];
    const float* dec_wq   = (const float*)d_in[16];
    const float* dec_wk   = (const float*)d_in[17];
    const float* dec_wv   = (const float*)d_in[18];
    const float* dec_wo   = (const float*)d_in[19];
    const float* dec_ln1g = (const float*)d_in[20];
    const float* dec_ln1b = (const float*)d_in[21];
    const float* dec_cq   = (const float*)d_in[22];
    const float* dec_ck   = (const float*)d_in[23];
    const float* dec_cv   = (const float*)d_in[24];
    const float* dec_co   = (const float*)d_in[25];
    const float* dec_ln2g = (const float*)d_in[26];
    const float* dec_ln2b = (const float*)d_in[27];
    const float* dec_w1   = (const float*)d_in[28];
    const float* dec_b1   = (const float*)d_in[29];
    const float* dec_w2   = (const float*)d_in[30];
    const float* dec_b2   = (const float*)d_in[31];
    const float* dec_ln3g = (const float*)d_in[32];
    const float* dec_ln3b = (const float*)d_in[33];
    const float* proj     = (const float*)d_in[34];

    float* OUT = (float*)d_out;
    char* base = (char*)d_ws;

    const size_t MSZ = (size_t)MTOK * DDIM;
    size_t off = 0;
    auto carve = [&](size_t bytes) { char* p = base + off; off += (bytes + 255) & ~(size_t)255; return p; };

    float* X      = (float*)carve(MSZ * 4);
    float* Yb     = (float*)carve(MSZ * 4);
    float* T1     = (float*)carve(MSZ * 4);
    u16*   Xb     = (u16*)  carve(MSZ * 2);
    u16*   Ybf    = (u16*)  carve(MSZ * 2);
    u16*   QKb    = (u16*)  carve((size_t)MTOK * 1024 * 2);
    u16*   Vt     = (u16*)  carve((size_t)512 * MTOK * 2);
    u16*   CTX    = (u16*)  carve(MSZ * 2);
    u16*   HFF    = (u16*)  carve((size_t)MTOK * FFN * 2);
    u16*   Kcr    = (u16*)  carve((size_t)NL * MTOK * 512 * 2);
    u16*   Vtc    = (u16*)  carve((size_t)NL * 512 * MTOK * 2);
    u16*   projT  = (u16*)  carve((size_t)NVOC * 512 * 2);
    float* PEt    = (float*)carve((size_t)SS * DDIM * 4);

    const size_t WFULL_B = (size_t)12 * WBLK * 2;
    bool full = (ws_size >= off + WFULL_B);
    u16* Wreg = (u16*)carve(full ? WFULL_B : (size_t)WBLK * 2);

    auto T = [&](const float* s, u16* d, int Kd, int Nd, size_t ss, size_t ds, int L) {
        transp<<<dim3(Nd / 64, Kd / 64, L), 256, 0, stream>>>(s, d, Nd, Kd, ss, ds);
    };

    // ---- one-time prep: PE table, proj^T, all weight transposes (batched) ----
    pe_kernel<<<SS, DDIM, 0, stream>>>(PEt);
    T(proj, projT, 512, NVOC, 0, 0, 1);
    if (full) {
        transpW<<<dim3(8, 8, 12 * NL), 256, 0, stream>>>(
            enc_wq, enc_wk, enc_wv, enc_wo,
            dec_wq, dec_wk, dec_wv, dec_wo,
            dec_cq, dec_ck, dec_cv, dec_co, Wreg);
        transpF1<<<dim3(32, 8, 2 * NL), 256, 0, stream>>>(enc_w1, dec_w1, Wreg);
        transpF2<<<dim3(8, 32, 2 * NL), 256, 0, stream>>>(enc_w2, dec_w2, Wreg);
    }

    // self-attention block: fused (QK-proj ∥ V^T-proj) dual GEMM + flash + O-proj -> T1
    auto self_attn = [&](const u16* xsrc, const u16* wb, const int* mask_ids, int causal) {
        mgemm_dual<64, 128><<<dim3(384), 256, 0, stream>>>(
            xsrc, 512, wb + OFF_QK, 512, QKb, 1024, 8, 256,
            wb + OFF_WV, 512, xsrc, 512, Vt, MTOK, 16,
            512);
        if (causal)
            flash_attn<1><<<dim3(8, 32), 256, 0, stream>>>(QKb, 1024, QKb + 512, 1024, Vt, CTX, mask_ids);
        else
            flash_attn<0><<<dim3(8, 32), 256, 0, stream>>>(QKb, 1024, QKb + 512, 1024, Vt, CTX, mask_ids);
        mgemm<64, 64, 0, 0, 0><<<dim3(8, 32, 1), 256, 0, stream>>>(
            CTX, 512, 0, 0, wb + OFF_WO, 512, 0, 0, T1, 512, 0, 0, 512, nullptr);
    };

    const size_t M2 = M2CNT, MF1 = MF1CNT;

    // ---- encoder ----
    embed_kernel<<<MTOK, DDIM, 0, stream>>>(src, emb_src, PEt, X, Xb);
    for (int l = 0; l < NL; l++) {
        u16* wb;
        if (full) wb = Wreg + (size_t)l * WBLK;
        else {
            wb = Wreg;
            T(enc_wq + l * M2,  wb + OFF_QK,          512, 512,  0, 0, 1);
            T(enc_wk + l * M2,  wb + OFF_QK + M2,     512, 512,  0, 0, 1);
            T(enc_wv + l * M2,  wb + OFF_WV,          512, 512,  0, 0, 1);
            T(enc_wo + l * M2,  wb + OFF_WO,          512, 512,  0, 0, 1);
            T(enc_w1 + l * MF1, wb + OFF_W1,          512, 2048, 0, 0, 1);
            T(enc_w2 + l * MF1, wb + OFF_W2,          2048, 512, 0, 0, 1);
        }
        self_attn(Xb, wb, src, 0);
        add_ln_kernel<<<MTOK, 256, 0, stream>>>(X, T1, enc_ln1g + l * DDIM, enc_ln1b + l * DDIM, Xb);
        mgemm<128, 128, 1, 1, 1><<<dim3(16, 16, 1), 256, 0, stream>>>(
            Xb, 512, 0, 0, wb + OFF_W1, 512, 0, 0, HFF, FFN, 0, 0, 512, enc_b1 + l * FFN);
        mgemm<64, 64, 0, 0, 1><<<dim3(8, 32, 1), 256, 0, stream>>>(
            HFF, FFN, 0, 0, wb + OFF_W2, FFN, 0, 0, T1, 512, 0, 0, FFN, enc_b2 + l * DDIM);
        add_ln_kernel<<<MTOK, 256, 0, stream>>>(X, T1, enc_ln2g + l * DDIM, enc_ln2b + l * DDIM, Xb);
    }

    // ---- cross-attention K / V^T for all 6 decoder layers (batched over z) ----
    if (full) {
        u16* Wd = Wreg + (size_t)NL * WBLK;
        mgemm<128, 128, 1, 0, 0><<<dim3(4, 16, NL), 256, 0, stream>>>(
            Xb, 512, 0, 0, Wd + OFF_CK, 512, 0, WBLK, Kcr, 512, 0, (size_t)MTOK * 512, 512, nullptr);
        mgemm<128, 128, 1, 0, 0><<<dim3(16, 4, NL), 256, 0, stream>>>(
            Wd + OFF_CV, 512, 0, WBLK, Xb, 512, 0, 0, Vtc, MTOK, 0, (size_t)512 * MTOK, 512, nullptr);
    }

    // ---- decoder ----
    embed_kernel<<<MTOK, DDIM, 0, stream>>>(trg, emb_trg, PEt, Yb, Ybf);
    for (int l = 0; l < NL; l++) {
        u16* wb;
        if (full) wb = Wreg + (size_t)(NL + l) * WBLK;
        else {
            wb = Wreg;
            T(dec_wq + l * M2,  wb + OFF_QK,          512, 512,  0, 0, 1);
            T(dec_wk + l * M2,  wb + OFF_QK + M2,     512, 512,  0, 0, 1);
            T(dec_wv + l * M2,  wb + OFF_WV,          512, 512,  0, 0, 1);
            T(dec_wo + l * M2,  wb + OFF_WO,          512, 512,  0, 0, 1);
            T(dec_cq + l * M2,  wb + OFF_CQ,          512, 512,  0, 0, 1);
            T(dec_ck + l * M2,  wb + OFF_CK,          512, 512,  0, 0, 1);
            T(dec_cv + l * M2,  wb + OFF_CV,          512, 512,  0, 0, 1);
            T(dec_co + l * M2,  wb + OFF_CO,          512, 512,  0, 0, 1);
            T(dec_w1 + l * MF1, wb + OFF_W1,          512, 2048, 0, 0, 1);
            T(dec_w2 + l * MF1, wb + OFF_W2,          2048, 512, 0, 0, 1);
            mgemm<128, 128, 1, 0, 0><<<dim3(4, 16, 1), 256, 0, stream>>>(
                Xb, 512, 0, 0, wb + OFF_CK, 512, 0, 0, Kcr + (size_t)l * MTOK * 512, 512, 0, 0, 512, nullptr);
            mgemm<128, 128, 1, 0, 0><<<dim3(16, 4, 1), 256, 0, stream>>>(
                wb + OFF_CV, 512, 0, 0, Xb, 512, 0, 0, Vtc + (size_t)l * 512 * MTOK, MTOK, 0, 0, 512, nullptr);
        }
        // masked self-attention
        self_attn(Ybf, wb, trg, 1);
        add_ln_kernel<<<MTOK, 256, 0, stream>>>(Yb, T1, dec_ln1g + l * DDIM, dec_ln1b + l * DDIM, Ybf);
        // cross-attention
        mgemm<64, 64, 1, 0, 0><<<dim3(8, 32, 1), 256, 0, stream>>>(
            Ybf, 512, 0, 0, wb + OFF_CQ, 512, 0, 0, QKb, 1024, 0, 0, 512, nullptr);
        flash_attn<0><<<dim3(8, 32), 256, 0, stream>>>(
            QKb, 1024, Kcr + (size_t)l * MTOK * 512, 512, Vtc + (size_t)l * 512 * MTOK, CTX, src);
        mgemm<64, 64, 0, 0, 0><<<dim3(8, 32, 1), 256, 0, stream>>>(
            CTX, 512, 0, 0, wb + OFF_CO, 512, 0, 0, T1, 512, 0, 0, 512, nullptr);
        add_ln_kernel<<<MTOK, 256, 0, stream>>>(Yb, T1, dec_ln2g + l * DDIM, dec_ln2b + l * DDIM, Ybf);
        // FFN
        mgemm<128, 128, 1, 1, 1><<<dim3(16, 16, 1), 256, 0, stream>>>(
            Ybf, 512, 0, 0, wb + OFF_W1, 512, 0, 0, HFF, FFN, 0, 0, 512, dec_b1 + l * FFN);
        mgemm<64, 64, 0, 0, 1><<<dim3(8, 32, 1), 256, 0, stream>>>(
            HFF, FFN, 0, 0, wb + OFF_W2, FFN, 0, 0, T1, 512, 0, 0, FFN, dec_b2 + l * DDIM);
        add_ln_kernel<<<MTOK, 256, 0, stream>>>(Yb, T1, dec_ln3g + l * DDIM, dec_ln3b + l * DDIM, Ybf);
    }

    // ---- final vocab projection (XCD-swizzled; 4000 blocks, 4000 % 8 == 0) ----
    mgemm<128, 128, 0, 0, 0, 1><<<dim3(NVOC / 128, 16, 1), 256, 0, stream>>>(
        Ybf, 512, 0, 0, projT, 512, 0, 0, OUT, NVOC, 0, 0, 512, nullptr);
}

// Round 5
// 1573.116 us; speedup vs baseline: 6.1040x; 1.0085x over previous
//
#include <hip/hip_runtime.h>
#include <math.h>

// ---------------- problem constants ----------------
#define BBATCH 4
#define SS 512
#define DDIM 512
#define FFN 2048
#define NHEAD 8
#define DHEAD 64
#define NL 6
#define NVOC 32000
#define MTOK (BBATCH*SS)       // 2048
#define PAD_ID 0
#define MSZE ((size_t)MTOK * DDIM)   // 1,048,576 elements

typedef unsigned short u16;
typedef __attribute__((ext_vector_type(8))) short short8;   // 8 bf16 (4 VGPRs)
typedef __attribute__((ext_vector_type(4))) float f32x4;

__device__ __forceinline__ u16 f2bf(float f) {
    union { float f; unsigned u; } v; v.f = f;
    unsigned r = ((v.u >> 16) & 1u) + 0x7fffu;   // round-to-nearest-even
    return (u16)((v.u + r) >> 16);
}

__device__ __forceinline__ void gload16(const u16* g, u16* l) {
    __builtin_amdgcn_global_load_lds(
        (const __attribute__((address_space(1))) void*)g,
        (__attribute__((address_space(3))) void*)l, 16, 0, 0);
}

// ======================= MFMA GEMM core (NT): C[M,N] = A[M,K] * B[N,K]^T =======================
// Double-buffered LDS: stage tile t+1 while computing tile t.
// LDS tiles [row][32k] with 16B-slot XOR swizzle: phys_slot = slot ^ ((row&3)<<4).
template<int BM, int BN, int OUTBF, int RELU, int BIAS>
__device__ __forceinline__ void gemm_core(
    u16* __restrict__ AsB, u16* __restrict__ BsB,
    const u16* __restrict__ A, int lda,
    const u16* __restrict__ B, int ldb,
    void* __restrict__ Cv, int ldc,
    int row0, int col0, int K, const float* __restrict__ bias)
{
    const int tid  = threadIdx.x;
    const int lane = tid & 63;
    const int wid  = tid >> 6;
    const int wr   = wid >> 1, wc = wid & 1;
    constexpr int MF = BM / 32, NF = BN / 32, RA = BM / 64, RB = BN / 64;

    const u16* aSrc[RA]; int aOff[RA];
    #pragma unroll
    for (int r = 0; r < RA; r++) {
        int row = (tid >> 2) + r * 64;
        int slot = ((tid & 3) << 4) ^ ((row & 3) << 4);
        aSrc[r] = A + (size_t)(row0 + row) * lda + (slot >> 1);
        aOff[r] = r * 2048 + tid * 8;
    }
    const u16* bSrc[RB]; int bOff[RB];
    #pragma unroll
    for (int r = 0; r < RB; r++) {
        int row = (tid >> 2) + r * 64;
        int slot = ((tid & 3) << 4) ^ ((row & 3) << 4);
        bSrc[r] = B + (size_t)(col0 + row) * ldb + (slot >> 1);
        bOff[r] = r * 2048 + tid * 8;
    }

    f32x4 acc[MF][NF];
    const f32x4 zero = {0.f, 0.f, 0.f, 0.f};
    #pragma unroll
    for (int m = 0; m < MF; m++)
        #pragma unroll
        for (int n = 0; n < NF; n++) acc[m][n] = zero;

    const int nt = K / 32;
    #pragma unroll
    for (int r = 0; r < RA; r++) gload16(aSrc[r], AsB + aOff[r]);
    #pragma unroll
    for (int r = 0; r < RB; r++) gload16(bSrc[r], BsB + bOff[r]);
    __syncthreads();

    for (int t = 0; t < nt; t++) {
        const int cur = t & 1;
        if (t + 1 < nt) {
            u16* ad = AsB + (cur ^ 1) * (BM * 32);
            u16* bd = BsB + (cur ^ 1) * (BN * 32);
            #pragma unroll
            for (int r = 0; r < RA; r++) gload16(aSrc[r] + (t + 1) * 32, ad + aOff[r]);
            #pragma unroll
            for (int r = 0; r < RB; r++) gload16(bSrc[r] + (t + 1) * 32, bd + bOff[r]);
        }
        const u16* as = AsB + cur * (BM * 32);
        const u16* bs = BsB + cur * (BN * 32);
        short8 af[MF], bf[NF];
        #pragma unroll
        for (int m = 0; m < MF; m++) {
            int row = wr * (BM / 2) + m * 16 + (lane & 15);
            int slot = ((lane >> 4) << 4) ^ ((row & 3) << 4);
            af[m] = *(const short8*)&as[row * 32 + (slot >> 1)];
        }
        #pragma unroll
        for (int n = 0; n < NF; n++) {
            int row = wc * (BN / 2) + n * 16 + (lane & 15);
            int slot = ((lane >> 4) << 4) ^ ((row & 3) << 4);
            bf[n] = *(const short8*)&bs[row * 32 + (slot >> 1)];
        }
        __builtin_amdgcn_s_setprio(1);
        #pragma unroll
        for (int m = 0; m < MF; m++)
            #pragma unroll
            for (int n = 0; n < NF; n++)
                acc[m][n] = __builtin_amdgcn_mfma_f32_16x16x32_bf16(af[m], bf[n], acc[m][n], 0, 0, 0);
        __builtin_amdgcn_s_setprio(0);
        __syncthreads();
    }

    const int crow = row0 + wr * (BM / 2);
    const int ccol = col0 + wc * (BN / 2);
    #pragma unroll
    for (int m = 0; m < MF; m++) {
        #pragma unroll
        for (int n = 0; n < NF; n++) {
            int col = ccol + n * 16 + (lane & 15);
            float bv = BIAS ? bias[col] : 0.0f;
            #pragma unroll
            for (int i = 0; i < 4; i++) {
                int row = crow + m * 16 + ((lane >> 4) << 2) + i;
                float v = acc[m][n][i] + bv;
                if (RELU) v = fmaxf(v, 0.0f);
                if (OUTBF) ((u16*)Cv)[(size_t)row * ldc + col] = f2bf(v);
                else       ((float*)Cv)[(size_t)row * ldc + col] = v;
            }
        }
    }
}

// batched/swizzled wrapper (z: zb = z>>3 batch stride, zh = z&7 head/split stride)
template<int BM, int BN, int OUTBF, int RELU, int BIAS, int SWZ = 0>
__global__ __launch_bounds__(256) void mgemm(
    const u16* __restrict__ A, int lda, size_t aSb, size_t aSh,
    const u16* __restrict__ B, int ldb, size_t bSb, size_t bSh,
    void* __restrict__ Cv, int ldc, size_t cSb, size_t cSh,
    int K, const float* __restrict__ bias)
{
    __shared__ __align__(16) u16 As[2 * BM * 32];
    __shared__ __align__(16) u16 Bs[2 * BN * 32];
    int bx = blockIdx.x, by = blockIdx.y;
    if (SWZ) {
        int nwg = gridDim.x * gridDim.y;
        int lin = by * gridDim.x + bx;
        int cpx = nwg >> 3;
        int s = (lin & 7) * cpx + (lin >> 3);
        bx = s % gridDim.x; by = s / gridDim.x;
    }
    const int zb = blockIdx.z >> 3, zh = blockIdx.z & 7;
    const u16* Ab = A + (size_t)zb * aSb + (size_t)zh * aSh;
    const u16* Bb = B + (size_t)zb * bSb + (size_t)zh * bSh;
    void* Cb = OUTBF ? (void*)((u16*)Cv + (size_t)zb * cSb + (size_t)zh * cSh)
                     : (void*)((float*)Cv + (size_t)zb * cSb + (size_t)zh * cSh);
    gemm_core<BM, BN, OUTBF, RELU, BIAS>(As, Bs, Ab, lda, Bb, ldb, Cb, ldc,
                                          by * BM, bx * BN, K, bias);
}

// dual-job GEMM: two independent NT gemms in one launch (bf16 out, no bias)
template<int BM, int BN>
__global__ __launch_bounds__(256) void mgemm_dual(
    const u16* __restrict__ A1, int lda1, const u16* __restrict__ B1, int ldb1,
    u16* __restrict__ C1, int ldc1, int nx1, int nblk1,
    const u16* __restrict__ A2, int lda2, const u16* __restrict__ B2, int ldb2,
    u16* __restrict__ C2, int ldc2, int nx2,
    int K)
{
    __shared__ __align__(16) u16 As[2 * BM * 32];
    __shared__ __align__(16) u16 Bs[2 * BN * 32];
    int id = blockIdx.x;
    if (id < nblk1) {
        gemm_core<BM, BN, 1, 0, 0>(As, Bs, A1, lda1, B1, ldb1, C1, ldc1,
                                    (id / nx1) * BM, (id % nx1) * BN, K, nullptr);
    } else {
        id -= nblk1;
        gemm_core<BM, BN, 1, 0, 0>(As, Bs, A2, lda2, B2, ldb2, C2, ldc2,
                                    (id / nx2) * BM, (id % nx2) * BN, K, nullptr);
    }
}

// ======================= fused flash attention (QBLK=128, 8 waves) =======================
template<int CAUSAL>
__global__ __launch_bounds__(512) void flash_attn(
    const u16* __restrict__ Qp, int ldq,
    const u16* __restrict__ Kp, int ldk,
    const u16* __restrict__ Vtp,
    u16* __restrict__ O,
    const int* __restrict__ ids)
{
    __shared__ __align__(16) u16 Kl[2][64 * 64];
    __shared__ __align__(16) u16 Vl[2][64 * 64];
    __shared__ __align__(16) u16 Pl[8][16 * 64];
    __shared__ float msk[SS];

    const int tid = threadIdx.x, lane = tid & 63, wid = tid >> 6;   // wid 0..7
    const int bh = blockIdx.y, b = bh >> 3, h = bh & 7;
    const int q0 = blockIdx.x * 128;

    for (int i = tid; i < SS; i += 512)
        msk[i] = (ids[b * SS + i] == PAD_ID) ? -1e30f : 0.0f;

    const int qloc = wid * 16 + (lane & 15);
    const u16* Qb = Qp + (size_t)(b * SS + q0 + qloc) * ldq + h * 64 + ((lane >> 4) * 8);
    short8 qf[2];
    qf[0] = *(const short8*)(Qb);
    qf[1] = *(const short8*)(Qb + 32);

    const u16* Kb = Kp + (size_t)b * SS * ldk + h * 64;
    const u16* Vb = Vtp + (size_t)(h * 64) * MTOK + b * SS;

    auto stage = [&](int buf, int kt) {
        int row = tid >> 3;                 // 0..63
        int sl  = tid & 7;
        int ls = sl ^ (row & 7);            // pre-swizzled source slot
        gload16(Kb + (size_t)(kt * 64 + row) * ldk + ls * 8, &Kl[buf][row * 64 + sl * 8]);
        gload16(Vb + (size_t)row * MTOK + kt * 64 + ls * 8, &Vl[buf][row * 64 + sl * 8]);
    };

    const int nt = CAUSAL ? (2 * blockIdx.x + 2) : (SS / 64);
    stage(0, 0);
    __syncthreads();

    float m_i[4], l_i[4];
    f32x4 o_acc[4];
    const f32x4 zero = {0.f, 0.f, 0.f, 0.f};
    #pragma unroll
    for (int i = 0; i < 4; i++) { m_i[i] = -1e30f; l_i[i] = 0.0f; }
    #pragma unroll
    for (int n = 0; n < 4; n++) o_acc[n] = zero;

    for (int kt = 0; kt < nt; kt++) {
        int cur = kt & 1;
        if (kt + 1 < nt) stage(cur ^ 1, kt + 1);

        // ---- S = Q K^T ----
        f32x4 s_acc[4];
        #pragma unroll
        for (int n = 0; n < 4; n++) s_acc[n] = zero;
        __builtin_amdgcn_s_setprio(1);
        #pragma unroll
        for (int kk = 0; kk < 2; kk++) {
            #pragma unroll
            for (int n = 0; n < 4; n++) {
                int row = n * 16 + (lane & 15);
                int ls = (kk * 4 + (lane >> 4)) ^ (row & 7);
                short8 kf = *(const short8*)&Kl[cur][row * 64 + ls * 8];
                s_acc[n] = __builtin_amdgcn_mfma_f32_16x16x32_bf16(qf[kk], kf, s_acc[n], 0, 0, 0);
            }
        }
        __builtin_amdgcn_s_setprio(0);

        // ---- online softmax (q = (lane>>4)*4 + i, k = n*16 + (lane&15)) ----
        float sv[4][4];
        #pragma unroll
        for (int n = 0; n < 4; n++) {
            int kg = kt * 64 + n * 16 + (lane & 15);
            float mk = msk[kg];
            #pragma unroll
            for (int i = 0; i < 4; i++) {
                float s = s_acc[n][i] * 0.125f + mk;
                if (CAUSAL) {
                    int qg = q0 + wid * 16 + ((lane >> 4) << 2) + i;
                    if (kg > qg) s = -1e30f;
                }
                sv[n][i] = s;
            }
        }
        float pm[4], mn[4], rs[4], ps[4];
        #pragma unroll
        for (int i = 0; i < 4; i++)
            pm[i] = fmaxf(fmaxf(sv[0][i], sv[1][i]), fmaxf(sv[2][i], sv[3][i]));
        #pragma unroll
        for (int i = 0; i < 4; i++) {
            #pragma unroll
            for (int msh = 1; msh <= 8; msh <<= 1)
                pm[i] = fmaxf(pm[i], __shfl_xor(pm[i], msh));
            mn[i] = fmaxf(m_i[i], pm[i]);
            rs[i] = __expf(m_i[i] - mn[i]);
            m_i[i] = mn[i];
        }
        float p[4][4];
        #pragma unroll
        for (int n = 0; n < 4; n++)
            #pragma unroll
            for (int i = 0; i < 4; i++)
                p[n][i] = (sv[n][i] < -1e29f) ? 0.0f : __expf(sv[n][i] - mn[i]);
        #pragma unroll
        for (int i = 0; i < 4; i++) {
            ps[i] = p[0][i] + p[1][i] + p[2][i] + p[3][i];
            #pragma unroll
            for (int msh = 1; msh <= 8; msh <<= 1)
                ps[i] += __shfl_xor(ps[i], msh);
            l_i[i] = l_i[i] * rs[i] + ps[i];
        }
        #pragma unroll
        for (int n = 0; n < 4; n++)
            #pragma unroll
            for (int i = 0; i < 4; i++)
                o_acc[n][i] *= rs[i];

        // ---- P -> LDS (swizzled, per-wave private), then PV ----
        #pragma unroll
        for (int n = 0; n < 4; n++) {
            int k = n * 16 + (lane & 15);
            #pragma unroll
            for (int i = 0; i < 4; i++) {
                int q = ((lane >> 4) << 2) + i;
                Pl[wid][q * 64 + (((k >> 3) ^ (q & 7)) << 3) + (k & 7)] = f2bf(p[n][i]);
            }
        }
        asm volatile("s_waitcnt lgkmcnt(0)" ::: "memory");
        __builtin_amdgcn_sched_barrier(0);

        __builtin_amdgcn_s_setprio(1);
        #pragma unroll
        for (int kk = 0; kk < 2; kk++) {
            int qrow = lane & 15;
            int lsp = (kk * 4 + (lane >> 4)) ^ (qrow & 7);
            short8 pa = *(const short8*)&Pl[wid][qrow * 64 + lsp * 8];
            #pragma unroll
            for (int nf = 0; nf < 4; nf++) {
                int row = nf * 16 + (lane & 15);
                int vs = (kk * 4 + (lane >> 4)) ^ (row & 7);
                short8 vf = *(const short8*)&Vl[cur][row * 64 + vs * 8];
                o_acc[nf] = __builtin_amdgcn_mfma_f32_16x16x32_bf16(pa, vf, o_acc[nf], 0, 0, 0);
            }
        }
        __builtin_amdgcn_s_setprio(0);
        __syncthreads();
    }

    #pragma unroll
    for (int nf = 0; nf < 4; nf++) {
        int d = h * 64 + nf * 16 + (lane & 15);
        #pragma unroll
        for (int i = 0; i < 4; i++) {
            int qg = b * SS + q0 + wid * 16 + ((lane >> 4) << 2) + i;
            O[(size_t)qg * DDIM + d] = f2bf(o_acc[nf][i] / l_i[i]);
        }
    }
}

// ============ transpose + convert core: dst[N,K] = bf16(src[K,N]) (64x64 tile) ============
__device__ __forceinline__ void transp_core(const float* __restrict__ src, u16* __restrict__ dst,
                                            int N, int K, int n0, int k0)
{
    __shared__ u16 t[64][65];
    const int tid = threadIdx.x;
    #pragma unroll
    for (int i = 0; i < 16; i++) {
        int idx = tid + i * 256;
        int kr = idx >> 6, nc = idx & 63;
        t[kr][nc] = f2bf(src[(size_t)(k0 + kr) * N + n0 + nc]);
    }
    __syncthreads();
    #pragma unroll
    for (int i = 0; i < 16; i++) {
        int idx = tid + i * 256;
        int nr = idx >> 6, kc = idx & 63;
        dst[(size_t)(n0 + nr) * K + k0 + kc] = t[kc][nr];
    }
}

__global__ __launch_bounds__(256) void transp(const float* __restrict__ src, u16* __restrict__ dst,
                                              int N, int K, size_t sStride, size_t dStride)
{
    transp_core(src + (size_t)blockIdx.z * sStride, dst + (size_t)blockIdx.z * dStride,
                N, K, blockIdx.x * 64, blockIdx.y * 64);
}

// ---- weight-block layout (u16 offsets) ----
#define OFF_QK 0u
#define OFF_WV 524288u
#define OFF_WO 786432u
#define OFF_CQ 1048576u
#define OFF_CK 1310720u
#define OFF_CV 1572864u
#define OFF_CO 1835008u
#define OFF_W1 2097152u
#define OFF_W2 3145728u
#define WBLK   4194304u
#define M2CNT  262144u
#define MF1CNT 1048576u

__global__ __launch_bounds__(256) void transpW(
    const float* p0, const float* p1, const float* p2, const float* p3,
    const float* p4, const float* p5, const float* p6, const float* p7,
    const float* p8, const float* p9, const float* p10, const float* p11,
    u16* __restrict__ wreg)
{
    int z = blockIdx.z;
    int w = z % 12, l = z / 12;
    const float* ptrs[12] = {p0,p1,p2,p3,p4,p5,p6,p7,p8,p9,p10,p11};
    const float* src = ptrs[w] + (size_t)l * M2CNT;
    u16* dst = wreg + (w < 4 ? (size_t)l * WBLK + (size_t)w * M2CNT
                             : (size_t)(NL + l) * WBLK + (size_t)(w - 4) * M2CNT);
    transp_core(src, dst, 512, 512, blockIdx.x * 64, blockIdx.y * 64);
}

__global__ __launch_bounds__(256) void transpF1(const float* __restrict__ e,
                                                const float* __restrict__ d, u16* __restrict__ wreg)
{
    int z = blockIdx.z; int l = z % NL, w = z / NL;
    const float* src = (w ? d : e) + (size_t)l * MF1CNT;
    u16* dst = wreg + (size_t)(w * NL + l) * WBLK + OFF_W1;
    transp_core(src, dst, 2048, 512, blockIdx.x * 64, blockIdx.y * 64);
}

__global__ __launch_bounds__(256) void transpF2(const float* __restrict__ e,
                                                const float* __restrict__ d, u16* __restrict__ wreg)
{
    int z = blockIdx.z; int l = z % NL, w = z / NL;
    const float* src = (w ? d : e) + (size_t)l * MF1CNT;
    u16* dst = wreg + (size_t)(w * NL + l) * WBLK + OFF_W2;
    transp_core(src, dst, 512, 2048, blockIdx.x * 64, blockIdx.y * 64);
}

// ============ positional-encoding table (fp64, once) ============
__global__ void pe_kernel(float* __restrict__ PEt)
{
    int pos = blockIdx.x, d = threadIdx.x;
    int i = d >> 1;
    double freq = exp(-(2.0 * (double)i / (double)DDIM) * log(10000.0));
    double ang = (double)pos * freq;
    PEt[pos * DDIM + d] = (float)((d & 1) ? cos(ang) : sin(ang));
}

// ============ merged embedding + PE for src and trg ============
__global__ void embed_kernel(const int* __restrict__ src, const int* __restrict__ trg,
                             const float* __restrict__ es, const float* __restrict__ et,
                             const float* __restrict__ PEt,
                             float* __restrict__ X, u16* __restrict__ Xb,
                             float* __restrict__ Y, u16* __restrict__ Ybf)
{
    int gtok = blockIdx.x;
    int d = threadIdx.x;
    bool dec = gtok >= MTOK;
    int tok = dec ? gtok - MTOK : gtok;
    int pos = tok & (SS - 1);
    int id = (dec ? trg : src)[tok];
    const float* emb = dec ? et : es;
    float val = emb[(size_t)id * DDIM + d] * 22.62741699796952f + PEt[pos * DDIM + d];
    (dec ? Y : X)[(size_t)tok * DDIM + d] = val;
    (dec ? Ybf : Xb)[(size_t)tok * DDIM + d] = f2bf(val);
}

// ============ residual add + LayerNorm (fp32 in place, bf16 shadow out) ============
__global__ __launch_bounds__(256) void add_ln_kernel(float* __restrict__ x,
    const float* __restrict__ addv, const float* __restrict__ g,
    const float* __restrict__ bta, u16* __restrict__ xb)
{
    int row = blockIdx.x;
    int tid = threadIdx.x;
    size_t base = (size_t)row * DDIM;
    __shared__ float sbuf[4];

    float v0 = x[base + tid]       + addv[base + tid];
    float v1 = x[base + tid + 256] + addv[base + tid + 256];

    float s = v0 + v1;
    #pragma unroll
    for (int o = 32; o > 0; o >>= 1) s += __shfl_down(s, o);
    if ((tid & 63) == 0) sbuf[tid >> 6] = s;
    __syncthreads();
    float mean = (sbuf[0] + sbuf[1] + sbuf[2] + sbuf[3]) * (1.0f / DDIM);
    __syncthreads();

    float d0 = v0 - mean, d1 = v1 - mean;
    float ss = d0 * d0 + d1 * d1;
    #pragma unroll
    for (int o = 32; o > 0; o >>= 1) ss += __shfl_down(ss, o);
    if ((tid & 63) == 0) sbuf[tid >> 6] = ss;
    __syncthreads();
    float var = (sbuf[0] + sbuf[1] + sbuf[2] + sbuf[3]) * (1.0f / DDIM);
    float inv = rsqrtf(var + 1e-5f);

    float o0 = d0 * inv * g[tid]       + bta[tid];
    float o1 = d1 * inv * g[tid + 256] + bta[tid + 256];
    x[base + tid] = o0;
    x[base + tid + 256] = o1;
    xb[base + tid] = f2bf(o0);
    xb[base + tid + 256] = f2bf(o1);
}

// ============ split-K reducer + bias + residual add + LayerNorm ============
__global__ __launch_bounds__(256) void add_ln_red(float* __restrict__ x,
    const float* __restrict__ part, const float* __restrict__ bias,
    const float* __restrict__ g, const float* __restrict__ bta, u16* __restrict__ xb)
{
    int row = blockIdx.x;
    int tid = threadIdx.x;
    size_t base = (size_t)row * DDIM;
    __shared__ float sbuf[4];

    float v0 = x[base + tid]       + bias[tid];
    float v1 = x[base + tid + 256] + bias[tid + 256];
    #pragma unroll
    for (int s4 = 0; s4 < 4; s4++) {
        v0 += part[s4 * MSZE + base + tid];
        v1 += part[s4 * MSZE + base + tid + 256];
    }

    float s = v0 + v1;
    #pragma unroll
    for (int o = 32; o > 0; o >>= 1) s += __shfl_down(s, o);
    if ((tid & 63) == 0) sbuf[tid >> 6] = s;
    __syncthreads();
    float mean = (sbuf[0] + sbuf[1] + sbuf[2] + sbuf[3]) * (1.0f / DDIM);
    __syncthreads();

    float d0 = v0 - mean, d1 = v1 - mean;
    float ss = d0 * d0 + d1 * d1;
    #pragma unroll
    for (int o = 32; o > 0; o >>= 1) ss += __shfl_down(ss, o);
    if ((tid & 63) == 0) sbuf[tid >> 6] = ss;
    __syncthreads();
    float var = (sbuf[0] + sbuf[1] + sbuf[2] + sbuf[3]) * (1.0f / DDIM);
    float inv = rsqrtf(var + 1e-5f);

    float o0 = d0 * inv * g[tid]       + bta[tid];
    float o1 = d1 * inv * g[tid + 256] + bta[tid + 256];
    x[base + tid] = o0;
    x[base + tid + 256] = o1;
    xb[base + tid] = f2bf(o0);
    xb[base + tid + 256] = f2bf(o1);
}

// ======================= host orchestration =======================
extern "C" void kernel_launch(void* const* d_in, const int* in_sizes, int n_in,
                              void* d_out, int out_size, void* d_ws, size_t ws_size,
                              hipStream_t stream)
{
    (void)in_sizes; (void)n_in; (void)out_size;

    const int*   src      = (const int*)  d_in[0];
    const int*   trg      = (const int*)  d_in[1];
    const float* emb_src  = (const float*)d_in[2];
    const float* emb_trg  = (const float*)d_in[3];
    const float* enc_wq   = (const float*)d_in[4];
    const float* enc_wk   = (const float*)d_in[5];
    const float* enc_wv   = (const float*)d_in[6];
    const float* enc_wo   = (const float*)d_in[7];
    const float* enc_ln1g = (const float*)d_in[8];
    const float* enc_ln1b = (const float*)d_in[9];
    const float* enc_w1   = (const float*)d_in[10];
    const float* enc_b1   = (const float*)d_in[11];
    const float* enc_w2   = (const float*)d_in[12];
    const float* enc_b2   = (const float*)d_in[13];
    const float* enc_ln2g = (const float*)d_in[14];
    const float* enc_ln2b = (const float*)d_in[15];
    const float* dec_wq   = (const float*)d_in[16];
    const float* dec_wk   = (const float*)d_in[17];
    const float* dec_wv   = (const float*)d_in[18];
    const float* dec_wo   = (const float*)d_in[19];
    const float* dec_ln1g = (const float*)d_in[20];
    const float* dec_ln1b = (const float*)d_in[21];
    const float* dec_cq   = (const float*)d_in[22];
    const float* dec_ck   = (const float*)d_in[23];
    const float* dec_cv   = (const float*)d_in[24];
    const float* dec_co   = (const float*)d_in[25];
    const float* dec_ln2g = (const float*)d_in[26];
    const float* dec_ln2b = (const float*)d_in[27];
    const float* dec_w1   = (const float*)d_in[28];
    const float* dec_b1   = (const float*)d_in[29];
    const float* dec_w2   = (const float*)d_in[30];
    const float* dec_b2   = (const float*)d_in[31];
    const float* dec_ln3g = (const float*)d_in[32];
    const float* dec_ln3b = (const float*)d_in[33];
    const float* proj     = (const float*)d_in[34];

    float* OUT = (float*)d_out;
    char* base = (char*)d_ws;

    size_t off = 0;
    auto carve = [&](size_t bytes) { char* p = base + off; off += (bytes + 255) & ~(size_t)255; return p; };

    float* X      = (float*)carve(MSZE * 4);
    float* Yb     = (float*)carve(MSZE * 4);
    float* T1     = (float*)carve(MSZE * 4);
    u16*   Xb     = (u16*)  carve(MSZE * 2);
    u16*   Ybf    = (u16*)  carve(MSZE * 2);
    u16*   QKb    = (u16*)  carve((size_t)MTOK * 1024 * 2);
    u16*   Vt     = (u16*)  carve((size_t)512 * MTOK * 2);
    u16*   CTX    = (u16*)  carve(MSZE * 2);
    u16*   HFF    = (u16*)  carve((size_t)MTOK * FFN * 2);
    u16*   Kcr    = (u16*)  carve((size_t)NL * MTOK * 512 * 2);
    u16*   Vtc    = (u16*)  carve((size_t)NL * 512 * MTOK * 2);
    u16*   projT  = (u16*)  carve((size_t)NVOC * 512 * 2);
    float* PEt    = (float*)carve((size_t)SS * DDIM * 4);
    float* Tp4    = (float*)carve((size_t)4 * MSZE * 4);       // split-K partials (16 MB)

    const size_t WFULL_B = (size_t)12 * WBLK * 2;
    bool full = (ws_size >= off + WFULL_B);
    u16* Wreg = (u16*)carve(full ? WFULL_B : (size_t)WBLK * 2);

    auto T = [&](const float* s, u16* d, int Kd, int Nd, size_t ss, size_t ds, int L) {
        transp<<<dim3(Nd / 64, Kd / 64, L), 256, 0, stream>>>(s, d, Nd, Kd, ss, ds);
    };

    // ---- one-time prep ----
    pe_kernel<<<SS, DDIM, 0, stream>>>(PEt);
    T(proj, projT, 512, NVOC, 0, 0, 1);
    if (full) {
        transpW<<<dim3(8, 8, 12 * NL), 256, 0, stream>>>(
            enc_wq, enc_wk, enc_wv, enc_wo,
            dec_wq, dec_wk, dec_wv, dec_wo,
            dec_cq, dec_ck, dec_cv, dec_co, Wreg);
        transpF1<<<dim3(32, 8, 2 * NL), 256, 0, stream>>>(enc_w1, dec_w1, Wreg);
        transpF2<<<dim3(8, 32, 2 * NL), 256, 0, stream>>>(enc_w2, dec_w2, Wreg);
    }
    // merged embeddings (no dependency on encoder)
    embed_kernel<<<2 * MTOK, DDIM, 0, stream>>>(src, trg, emb_src, emb_trg, PEt, X, Xb, Yb, Ybf);

    // self-attention block: (QK-proj ∥ V^T-proj) dual 128² GEMM + flash + O-proj -> T1
    auto self_attn = [&](const u16* xsrc, const u16* wb, const int* mask_ids, int causal) {
        mgemm_dual<128, 128><<<dim3(192), 256, 0, stream>>>(
            xsrc, 512, wb + OFF_QK, 512, QKb, 1024, 8, 128,
            wb + OFF_WV, 512, xsrc, 512, Vt, MTOK, 16,
            512);
        if (causal)
            flash_attn<1><<<dim3(4, 32), 512, 0, stream>>>(QKb, 1024, QKb + 512, 1024, Vt, CTX, mask_ids);
        else
            flash_attn<0><<<dim3(4, 32), 512, 0, stream>>>(QKb, 1024, QKb + 512, 1024, Vt, CTX, mask_ids);
        mgemm<64, 64, 0, 0, 0><<<dim3(8, 32, 1), 256, 0, stream>>>(
            CTX, 512, 0, 0, wb + OFF_WO, 512, 0, 0, T1, 512, 0, 0, 512, nullptr);
    };

    // FFN: W1 GEMM (128², relu+bias) then W2 split-K(4x512) 128² -> Tp4, reduced in add_ln_red
    auto ffn = [&](const u16* xsrc, const u16* wb, const float* b1) {
        mgemm<128, 128, 1, 1, 1><<<dim3(16, 16, 1), 256, 0, stream>>>(
            xsrc, 512, 0, 0, wb + OFF_W1, 512, 0, 0, HFF, FFN, 0, 0, 512, b1);
        mgemm<128, 128, 0, 0, 0><<<dim3(4, 16, 4), 256, 0, stream>>>(
            HFF, 2048, 0, 512, wb + OFF_W2, 2048, 0, 512,
            Tp4, 512, 0, MSZE, 512, nullptr);
    };

    const size_t M2 = M2CNT, MF1 = MF1CNT;

    // ---- encoder ----
    for (int l = 0; l < NL; l++) {
        u16* wb;
        if (full) wb = Wreg + (size_t)l * WBLK;
        else {
            wb = Wreg;
            T(enc_wq + l * M2,  wb + OFF_QK,          512, 512,  0, 0, 1);
            T(enc_wk + l * M2,  wb + OFF_QK + M2,     512, 512,  0, 0, 1);
            T(enc_wv + l * M2,  wb + OFF_WV,          512, 512,  0, 0, 1);
            T(enc_wo + l * M2,  wb + OFF_WO,          512, 512,  0, 0, 1);
            T(enc_w1 + l * MF1, wb + OFF_W1,          512, 2048, 0, 0, 1);
            T(enc_w2 + l * MF1, wb + OFF_W2,          2048, 512, 0, 0, 1);
        }
        self_attn(Xb, wb, src, 0);
        add_ln_kernel<<<MTOK, 256, 0, stream>>>(X, T1, enc_ln1g + l * DDIM, enc_ln1b + l * DDIM, Xb);
        ffn(Xb, wb, enc_b1 + l * FFN);
        add_ln_red<<<MTOK, 256, 0, stream>>>(X, Tp4, enc_b2 + l * DDIM,
                                             enc_ln2g + l * DDIM, enc_ln2b + l * DDIM, Xb);
    }

    // ---- cross-attention K / V^T for all 6 decoder layers (batched over z) ----
    if (full) {
        u16* Wd = Wreg + (size_t)NL * WBLK;
        mgemm<128, 128, 1, 0, 0><<<dim3(4, 16, NL), 256, 0, stream>>>(
            Xb, 512, 0, 0, Wd + OFF_CK, 512, 0, WBLK, Kcr, 512, 0, (size_t)MTOK * 512, 512, nullptr);
        mgemm<128, 128, 1, 0, 0><<<dim3(16, 4, NL), 256, 0, stream>>>(
            Wd + OFF_CV, 512, 0, WBLK, Xb, 512, 0, 0, Vtc, MTOK, 0, (size_t)512 * MTOK, 512, nullptr);
    }

    // ---- decoder ----
    for (int l = 0; l < NL; l++) {
        u16* wb;
        if (full) wb = Wreg + (size_t)(NL + l) * WBLK;
        else {
            wb = Wreg;
            T(dec_wq + l * M2,  wb + OFF_QK,          512, 512,  0, 0, 1);
            T(dec_wk + l * M2,  wb + OFF_QK + M2,     512, 512,  0, 0, 1);
            T(dec_wv + l * M2,  wb + OFF_WV,          512, 512,  0, 0, 1);
            T(dec_wo + l * M2,  wb + OFF_WO,          512, 512,  0, 0, 1);
            T(dec_cq + l * M2,  wb + OFF_CQ,          512, 512,  0, 0, 1);
            T(dec_ck + l * M2,  wb + OFF_CK,          512, 512,  0, 0, 1);
            T(dec_cv + l * M2,  wb + OFF_CV,          512, 512,  0, 0, 1);
            T(dec_co + l * M2,  wb + OFF_CO,          512, 512,  0, 0, 1);
            T(dec_w1 + l * MF1, wb + OFF_W1,          512, 2048, 0, 0, 1);
            T(dec_w2 + l * MF1, wb + OFF_W2,          2048, 512, 0, 0, 1);
            mgemm<128, 128, 1, 0, 0><<<dim3(4, 16, 1), 256, 0, stream>>>(
                Xb, 512, 0, 0, wb + OFF_CK, 512, 0, 0, Kcr + (size_t)l * MTOK * 512, 512, 0, 0, 512, nullptr);
            mgemm<128, 128, 1, 0, 0><<<dim3(16, 4, 1), 256, 0, stream>>>(
                wb + OFF_CV, 512, 0, 0, Xb, 512, 0, 0, Vtc + (size_t)l * 512 * MTOK, MTOK, 0, 0, 512, nullptr);
        }
        // masked self-attention
        self_attn(Ybf, wb, trg, 1);
        add_ln_kernel<<<MTOK, 256, 0, stream>>>(Yb, T1, dec_ln1g + l * DDIM, dec_ln1b + l * DDIM, Ybf);
        // cross-attention
        mgemm<64, 64, 1, 0, 0><<<dim3(8, 32, 1), 256, 0, stream>>>(
            Ybf, 512, 0, 0, wb + OFF_CQ, 512, 0, 0, QKb, 1024, 0, 0, 512, nullptr);
        flash_attn<0><<<dim3(4, 32), 512, 0, stream>>>(
            QKb, 1024, Kcr + (size_t)l * MTOK * 512, 512, Vtc + (size_t)l * 512 * MTOK, CTX, src);
        mgemm<64, 64, 0, 0, 0><<<dim3(8, 32, 1), 256, 0, stream>>>(
            CTX, 512, 0, 0, wb + OFF_CO, 512, 0, 0, T1, 512, 0, 0, 512, nullptr);
        add_ln_kernel<<<MTOK, 256, 0, stream>>>(Yb, T1, dec_ln2g + l * DDIM, dec_ln2b + l * DDIM, Ybf);
        // FFN
        ffn(Ybf, wb, dec_b1 + l * FFN);
        add_ln_red<<<MTOK, 256, 0, stream>>>(Yb, Tp4, dec_b2 + l * DDIM,
                                             dec_ln3g + l * DDIM, dec_ln3b + l * DDIM, Ybf);
    }

    // ---- final vocab projection (XCD-swizzled) ----
    mgemm<128, 128, 0, 0, 0, 1><<<dim3(NVOC / 128, 16, 1), 256, 0, stream>>>(
        Ybf, 512, 0, 0, projT, 512, 0, 0, OUT, NVOC, 0, 0, 512, nullptr);
}

// Round 6
// 1547.406 us; speedup vs baseline: 6.2054x; 1.0166x over previous
//
#include <hip/hip_runtime.h>
#include <math.h>

// ---------------- problem constants ----------------
#define BBATCH 4
#define SS 512
#define DDIM 512
#define FFN 2048
#define NHEAD 8
#define DHEAD 64
#define NL 6
#define NVOC 32000
#define MTOK (BBATCH*SS)       // 2048
#define PAD_ID 0
#define MSZE ((size_t)MTOK * DDIM)   // 1,048,576 elements

typedef unsigned short u16;
typedef __attribute__((ext_vector_type(8))) short short8;   // 8 bf16 (4 VGPRs)
typedef __attribute__((ext_vector_type(4))) float f32x4;

__device__ __forceinline__ u16 f2bf(float f) {
    union { float f; unsigned u; } v; v.f = f;
    unsigned r = ((v.u >> 16) & 1u) + 0x7fffu;   // round-to-nearest-even
    return (u16)((v.u + r) >> 16);
}

__device__ __forceinline__ void gload16(const u16* g, u16* l) {
    __builtin_amdgcn_global_load_lds(
        (const __attribute__((address_space(1))) void*)g,
        (__attribute__((address_space(3))) void*)l, 16, 0, 0);
}

// counted vmcnt wait (literal-immediate) + scheduling fence (rule #18)
template<int N> __device__ __forceinline__ void waitv() {
    if constexpr (N == 0)      asm volatile("s_waitcnt vmcnt(0)" ::: "memory");
    else if constexpr (N == 2) asm volatile("s_waitcnt vmcnt(2)" ::: "memory");
    else if constexpr (N == 3) asm volatile("s_waitcnt vmcnt(3)" ::: "memory");
    else if constexpr (N == 4) asm volatile("s_waitcnt vmcnt(4)" ::: "memory");
    else if constexpr (N == 6) asm volatile("s_waitcnt vmcnt(6)" ::: "memory");
    else if constexpr (N == 8) asm volatile("s_waitcnt vmcnt(8)" ::: "memory");
    __builtin_amdgcn_sched_barrier(0);
}
__device__ __forceinline__ void rawbar() {
    __builtin_amdgcn_s_barrier();
    __builtin_amdgcn_sched_barrier(0);
}

// ======================= MFMA GEMM core (NT): C[M,N] = A[M,K] * B[N,K]^T =======================
// 4-slot LDS ring, 3 tiles in flight (counted vmcnt, never drained to 0 in the main loop).
// LDS tiles [row][32k] with 16B-slot XOR swizzle: phys_slot = slot ^ ((row&3)<<4).
template<int BM, int BN, int OUTBF, int RELU, int BIAS>
__device__ __forceinline__ void gemm_core(
    u16* __restrict__ AsB, u16* __restrict__ BsB,     // 4*BM*32 / 4*BN*32
    const u16* __restrict__ A, int lda,
    const u16* __restrict__ B, int ldb,
    void* __restrict__ Cv, int ldc,
    int row0, int col0, int K, const float* __restrict__ bias)
{
    const int tid  = threadIdx.x;
    const int lane = tid & 63;
    const int wid  = tid >> 6;
    const int wr   = wid >> 1, wc = wid & 1;
    constexpr int MF = BM / 32, NF = BN / 32, RA = BM / 64, RB = BN / 64;
    constexpr int LPT = RA + RB;     // loads per tile per thread (wave-instr count)

    const u16* aSrc[RA]; int aOff[RA];
    #pragma unroll
    for (int r = 0; r < RA; r++) {
        int row = (tid >> 2) + r * 64;
        int slot = ((tid & 3) << 4) ^ ((row & 3) << 4);
        aSrc[r] = A + (size_t)(row0 + row) * lda + (slot >> 1);
        aOff[r] = r * 2048 + tid * 8;
    }
    const u16* bSrc[RB]; int bOff[RB];
    #pragma unroll
    for (int r = 0; r < RB; r++) {
        int row = (tid >> 2) + r * 64;
        int slot = ((tid & 3) << 4) ^ ((row & 3) << 4);
        bSrc[r] = B + (size_t)(col0 + row) * ldb + (slot >> 1);
        bOff[r] = r * 2048 + tid * 8;
    }

    f32x4 acc[MF][NF];
    const f32x4 zero = {0.f, 0.f, 0.f, 0.f};
    #pragma unroll
    for (int m = 0; m < MF; m++)
        #pragma unroll
        for (int n = 0; n < NF; n++) acc[m][n] = zero;

    auto issue = [&](int t) {
        u16* ad = AsB + (t & 3) * (BM * 32);
        u16* bd = BsB + (t & 3) * (BN * 32);
        #pragma unroll
        for (int r = 0; r < RA; r++) gload16(aSrc[r] + t * 32, ad + aOff[r]);
        #pragma unroll
        for (int r = 0; r < RB; r++) gload16(bSrc[r] + t * 32, bd + bOff[r]);
    };
    auto comp = [&](int t) {
        const u16* as = AsB + (t & 3) * (BM * 32);
        const u16* bs = BsB + (t & 3) * (BN * 32);
        short8 af[MF], bf[NF];
        #pragma unroll
        for (int m = 0; m < MF; m++) {
            int row = wr * (BM / 2) + m * 16 + (lane & 15);
            int slot = ((lane >> 4) << 4) ^ ((row & 3) << 4);
            af[m] = *(const short8*)&as[row * 32 + (slot >> 1)];
        }
        #pragma unroll
        for (int n = 0; n < NF; n++) {
            int row = wc * (BN / 2) + n * 16 + (lane & 15);
            int slot = ((lane >> 4) << 4) ^ ((row & 3) << 4);
            bf[n] = *(const short8*)&bs[row * 32 + (slot >> 1)];
        }
        __builtin_amdgcn_s_setprio(1);
        #pragma unroll
        for (int m = 0; m < MF; m++)
            #pragma unroll
            for (int n = 0; n < NF; n++)
                acc[m][n] = __builtin_amdgcn_mfma_f32_16x16x32_bf16(af[m], bf[n], acc[m][n], 0, 0, 0);
        __builtin_amdgcn_s_setprio(0);
    };

    const int nt = K / 32;   // always >= 3 here
    issue(0); issue(1); issue(2);
    int t = 0;
    for (; t < nt - 2; ++t) {
        waitv<2 * LPT>();    // tile t complete; t+1, t+2 still in flight
        rawbar();
        if (t + 3 < nt) issue(t + 3);
        comp(t);
    }
    waitv<LPT>(); rawbar(); comp(nt - 2);
    waitv<0>();   rawbar(); comp(nt - 1);

    const int crow = row0 + wr * (BM / 2);
    const int ccol = col0 + wc * (BN / 2);
    #pragma unroll
    for (int m = 0; m < MF; m++) {
        #pragma unroll
        for (int n = 0; n < NF; n++) {
            int col = ccol + n * 16 + (lane & 15);
            float bv = BIAS ? bias[col] : 0.0f;
            #pragma unroll
            for (int i = 0; i < 4; i++) {
                int row = crow + m * 16 + ((lane >> 4) << 2) + i;
                float v = acc[m][n][i] + bv;
                if (RELU) v = fmaxf(v, 0.0f);
                if (OUTBF) ((u16*)Cv)[(size_t)row * ldc + col] = f2bf(v);
                else       ((float*)Cv)[(size_t)row * ldc + col] = v;
            }
        }
    }
}

// batched/swizzled wrapper (z: zb = z>>3 batch stride, zh = z&7 head/split stride)
template<int BM, int BN, int OUTBF, int RELU, int BIAS, int SWZ = 0>
__global__ __launch_bounds__(256) void mgemm(
    const u16* __restrict__ A, int lda, size_t aSb, size_t aSh,
    const u16* __restrict__ B, int ldb, size_t bSb, size_t bSh,
    void* __restrict__ Cv, int ldc, size_t cSb, size_t cSh,
    int K, const float* __restrict__ bias)
{
    __shared__ __align__(16) u16 As[4 * BM * 32];
    __shared__ __align__(16) u16 Bs[4 * BN * 32];
    int bx = blockIdx.x, by = blockIdx.y;
    if (SWZ) {
        int nwg = gridDim.x * gridDim.y;
        int lin = by * gridDim.x + bx;
        int cpx = nwg >> 3;
        int s = (lin & 7) * cpx + (lin >> 3);
        bx = s % gridDim.x; by = s / gridDim.x;
    }
    const int zb = blockIdx.z >> 3, zh = blockIdx.z & 7;
    const u16* Ab = A + (size_t)zb * aSb + (size_t)zh * aSh;
    const u16* Bb = B + (size_t)zb * bSb + (size_t)zh * bSh;
    void* Cb = OUTBF ? (void*)((u16*)Cv + (size_t)zb * cSb + (size_t)zh * cSh)
                     : (void*)((float*)Cv + (size_t)zb * cSb + (size_t)zh * cSh);
    gemm_core<BM, BN, OUTBF, RELU, BIAS>(As, Bs, Ab, lda, Bb, ldb, Cb, ldc,
                                          by * BM, bx * BN, K, bias);
}

// dual-job GEMM: two independent NT gemms in one launch (bf16 out, no bias)
template<int BM, int BN>
__global__ __launch_bounds__(256) void mgemm_dual(
    const u16* __restrict__ A1, int lda1, const u16* __restrict__ B1, int ldb1,
    u16* __restrict__ C1, int ldc1, int nx1, int nblk1,
    const u16* __restrict__ A2, int lda2, const u16* __restrict__ B2, int ldb2,
    u16* __restrict__ C2, int ldc2, int nx2,
    int K)
{
    __shared__ __align__(16) u16 As[4 * BM * 32];
    __shared__ __align__(16) u16 Bs[4 * BN * 32];
    int id = blockIdx.x;
    if (id < nblk1) {
        gemm_core<BM, BN, 1, 0, 0>(As, Bs, A1, lda1, B1, ldb1, C1, ldc1,
                                    (id / nx1) * BM, (id % nx1) * BN, K, nullptr);
    } else {
        id -= nblk1;
        gemm_core<BM, BN, 1, 0, 0>(As, Bs, A2, lda2, B2, ldb2, C2, ldc2,
                                    (id / nx2) * BM, (id % nx2) * BN, K, nullptr);
    }
}

// ======================= fused flash attention (QBLK=128, 8 waves) =======================
// 3-slot K/V LDS ring with counted vmcnt (2 stages in flight, steady wait = vmcnt(2)).
template<int CAUSAL>
__global__ __launch_bounds__(512) void flash_attn(
    const u16* __restrict__ Qp, int ldq,
    const u16* __restrict__ Kp, int ldk,
    const u16* __restrict__ Vtp,
    u16* __restrict__ O,
    const int* __restrict__ ids)
{
    __shared__ __align__(16) u16 Kl[3][64 * 64];
    __shared__ __align__(16) u16 Vl[3][64 * 64];
    __shared__ __align__(16) u16 Pl[8][16 * 64];
    __shared__ float msk[SS];

    const int tid = threadIdx.x, lane = tid & 63, wid = tid >> 6;   // wid 0..7
    const int bh = blockIdx.y, b = bh >> 3, h = bh & 7;
    const int q0 = blockIdx.x * 128;

    for (int i = tid; i < SS; i += 512)
        msk[i] = (ids[b * SS + i] == PAD_ID) ? -1e30f : 0.0f;

    const int qloc = wid * 16 + (lane & 15);
    const u16* Qb = Qp + (size_t)(b * SS + q0 + qloc) * ldq + h * 64 + ((lane >> 4) * 8);
    short8 qf[2];
    qf[0] = *(const short8*)(Qb);
    qf[1] = *(const short8*)(Qb + 32);

    const u16* Kb = Kp + (size_t)b * SS * ldk + h * 64;
    const u16* Vb = Vtp + (size_t)(h * 64) * MTOK + b * SS;

    auto stage = [&](int buf, int kt) {
        int row = tid >> 3;                 // 0..63
        int sl  = tid & 7;
        int ls = sl ^ (row & 7);            // pre-swizzled source slot
        gload16(Kb + (size_t)(kt * 64 + row) * ldk + ls * 8, &Kl[buf][row * 64 + sl * 8]);
        gload16(Vb + (size_t)row * MTOK + kt * 64 + ls * 8, &Vl[buf][row * 64 + sl * 8]);
    };

    const int nt = CAUSAL ? (2 * blockIdx.x + 2) : (SS / 64);

    float m_i[4], l_i[4];
    f32x4 o_acc[4];
    const f32x4 zero = {0.f, 0.f, 0.f, 0.f};
    #pragma unroll
    for (int i = 0; i < 4; i++) { m_i[i] = -1e30f; l_i[i] = 0.0f; }
    #pragma unroll
    for (int n = 0; n < 4; n++) o_acc[n] = zero;

    auto comp = [&](int kt) {
        const int cur = kt % 3;
        // ---- S = Q K^T ----
        f32x4 s_acc[4];
        #pragma unroll
        for (int n = 0; n < 4; n++) s_acc[n] = zero;
        __builtin_amdgcn_s_setprio(1);
        #pragma unroll
        for (int kk = 0; kk < 2; kk++) {
            #pragma unroll
            for (int n = 0; n < 4; n++) {
                int row = n * 16 + (lane & 15);
                int ls = (kk * 4 + (lane >> 4)) ^ (row & 7);
                short8 kf = *(const short8*)&Kl[cur][row * 64 + ls * 8];
                s_acc[n] = __builtin_amdgcn_mfma_f32_16x16x32_bf16(qf[kk], kf, s_acc[n], 0, 0, 0);
            }
        }
        __builtin_amdgcn_s_setprio(0);

        // ---- online softmax (q = (lane>>4)*4 + i, k = n*16 + (lane&15)) ----
        float sv[4][4];
        #pragma unroll
        for (int n = 0; n < 4; n++) {
            int kg = kt * 64 + n * 16 + (lane & 15);
            float mk = msk[kg];
            #pragma unroll
            for (int i = 0; i < 4; i++) {
                float s = s_acc[n][i] * 0.125f + mk;
                if (CAUSAL) {
                    int qg = q0 + wid * 16 + ((lane >> 4) << 2) + i;
                    if (kg > qg) s = -1e30f;
                }
                sv[n][i] = s;
            }
        }
        float pm[4], mn[4], rs[4], ps[4];
        #pragma unroll
        for (int i = 0; i < 4; i++)
            pm[i] = fmaxf(fmaxf(sv[0][i], sv[1][i]), fmaxf(sv[2][i], sv[3][i]));
        #pragma unroll
        for (int i = 0; i < 4; i++) {
            #pragma unroll
            for (int msh = 1; msh <= 8; msh <<= 1)
                pm[i] = fmaxf(pm[i], __shfl_xor(pm[i], msh));
            mn[i] = fmaxf(m_i[i], pm[i]);
            rs[i] = __expf(m_i[i] - mn[i]);
            m_i[i] = mn[i];
        }
        float p[4][4];
        #pragma unroll
        for (int n = 0; n < 4; n++)
            #pragma unroll
            for (int i = 0; i < 4; i++)
                p[n][i] = (sv[n][i] < -1e29f) ? 0.0f : __expf(sv[n][i] - mn[i]);
        #pragma unroll
        for (int i = 0; i < 4; i++) {
            ps[i] = p[0][i] + p[1][i] + p[2][i] + p[3][i];
            #pragma unroll
            for (int msh = 1; msh <= 8; msh <<= 1)
                ps[i] += __shfl_xor(ps[i], msh);
            l_i[i] = l_i[i] * rs[i] + ps[i];
        }
        #pragma unroll
        for (int n = 0; n < 4; n++)
            #pragma unroll
            for (int i = 0; i < 4; i++)
                o_acc[n][i] *= rs[i];

        // ---- P -> LDS (swizzled, per-wave private), then PV ----
        #pragma unroll
        for (int n = 0; n < 4; n++) {
            int k = n * 16 + (lane & 15);
            #pragma unroll
            for (int i = 0; i < 4; i++) {
                int q = ((lane >> 4) << 2) + i;
                Pl[wid][q * 64 + (((k >> 3) ^ (q & 7)) << 3) + (k & 7)] = f2bf(p[n][i]);
            }
        }
        asm volatile("s_waitcnt lgkmcnt(0)" ::: "memory");
        __builtin_amdgcn_sched_barrier(0);

        __builtin_amdgcn_s_setprio(1);
        #pragma unroll
        for (int kk = 0; kk < 2; kk++) {
            int qrow = lane & 15;
            int lsp = (kk * 4 + (lane >> 4)) ^ (qrow & 7);
            short8 pa = *(const short8*)&Pl[wid][qrow * 64 + lsp * 8];
            #pragma unroll
            for (int nf = 0; nf < 4; nf++) {
                int row = nf * 16 + (lane & 15);
                int vs = (kk * 4 + (lane >> 4)) ^ (row & 7);
                short8 vf = *(const short8*)&Vl[cur][row * 64 + vs * 8];
                o_acc[nf] = __builtin_amdgcn_mfma_f32_16x16x32_bf16(pa, vf, o_acc[nf], 0, 0, 0);
            }
        }
        __builtin_amdgcn_s_setprio(0);
    };

    stage(0, 0);
    stage(1, 1);
    int t = 0;
    for (; t < nt - 1; ++t) {
        waitv<2>();          // stage t complete; stage t+1 in flight
        rawbar();
        if (t + 2 < nt) stage((t + 2) % 3, t + 2);
        comp(t);
    }
    waitv<0>(); rawbar(); comp(nt - 1);

    #pragma unroll
    for (int nf = 0; nf < 4; nf++) {
        int d = h * 64 + nf * 16 + (lane & 15);
        #pragma unroll
        for (int i = 0; i < 4; i++) {
            int qg = b * SS + q0 + wid * 16 + ((lane >> 4) << 2) + i;
            O[(size_t)qg * DDIM + d] = f2bf(o_acc[nf][i] / l_i[i]);
        }
    }
}

// ============ transpose + convert core: dst[N,K] = bf16(src[K,N]) (64x64 tile) ============
__device__ __forceinline__ void transp_core(const float* __restrict__ src, u16* __restrict__ dst,
                                            int N, int K, int n0, int k0)
{
    __shared__ u16 t[64][65];
    const int tid = threadIdx.x;
    #pragma unroll
    for (int i = 0; i < 16; i++) {
        int idx = tid + i * 256;
        int kr = idx >> 6, nc = idx & 63;
        t[kr][nc] = f2bf(src[(size_t)(k0 + kr) * N + n0 + nc]);
    }
    __syncthreads();
    #pragma unroll
    for (int i = 0; i < 16; i++) {
        int idx = tid + i * 256;
        int nr = idx >> 6, kc = idx & 63;
        dst[(size_t)(n0 + nr) * K + k0 + kc] = t[kc][nr];
    }
}

__global__ __launch_bounds__(256) void transp(const float* __restrict__ src, u16* __restrict__ dst,
                                              int N, int K, size_t sStride, size_t dStride)
{
    transp_core(src + (size_t)blockIdx.z * sStride, dst + (size_t)blockIdx.z * dStride,
                N, K, blockIdx.x * 64, blockIdx.y * 64);
}

// ---- weight-block layout (u16 offsets) ----
#define OFF_QK 0u
#define OFF_WV 524288u
#define OFF_WO 786432u
#define OFF_CQ 1048576u
#define OFF_CK 1310720u
#define OFF_CV 1572864u
#define OFF_CO 1835008u
#define OFF_W1 2097152u
#define OFF_W2 3145728u
#define WBLK   4194304u
#define M2CNT  262144u
#define MF1CNT 1048576u

__global__ __launch_bounds__(256) void transpW(
    const float* p0, const float* p1, const float* p2, const float* p3,
    const float* p4, const float* p5, const float* p6, const float* p7,
    const float* p8, const float* p9, const float* p10, const float* p11,
    u16* __restrict__ wreg)
{
    int z = blockIdx.z;
    int w = z % 12, l = z / 12;
    const float* ptrs[12] = {p0,p1,p2,p3,p4,p5,p6,p7,p8,p9,p10,p11};
    const float* src = ptrs[w] + (size_t)l * M2CNT;
    u16* dst = wreg + (w < 4 ? (size_t)l * WBLK + (size_t)w * M2CNT
                             : (size_t)(NL + l) * WBLK + (size_t)(w - 4) * M2CNT);
    transp_core(src, dst, 512, 512, blockIdx.x * 64, blockIdx.y * 64);
}

__global__ __launch_bounds__(256) void transpF1(const float* __restrict__ e,
                                                const float* __restrict__ d, u16* __restrict__ wreg)
{
    int z = blockIdx.z; int l = z % NL, w = z / NL;
    const float* src = (w ? d : e) + (size_t)l * MF1CNT;
    u16* dst = wreg + (size_t)(w * NL + l) * WBLK + OFF_W1;
    transp_core(src, dst, 2048, 512, blockIdx.x * 64, blockIdx.y * 64);
}

__global__ __launch_bounds__(256) void transpF2(const float* __restrict__ e,
                                                const float* __restrict__ d, u16* __restrict__ wreg)
{
    int z = blockIdx.z; int l = z % NL, w = z / NL;
    const float* src = (w ? d : e) + (size_t)l * MF1CNT;
    u16* dst = wreg + (size_t)(w * NL + l) * WBLK + OFF_W2;
    transp_core(src, dst, 512, 2048, blockIdx.x * 64, blockIdx.y * 64);
}

// ============ positional-encoding table (fp64, once) ============
__global__ void pe_kernel(float* __restrict__ PEt)
{
    int pos = blockIdx.x, d = threadIdx.x;
    int i = d >> 1;
    double freq = exp(-(2.0 * (double)i / (double)DDIM) * log(10000.0));
    double ang = (double)pos * freq;
    PEt[pos * DDIM + d] = (float)((d & 1) ? cos(ang) : sin(ang));
}

// ============ merged embedding + PE for src and trg ============
__global__ void embed_kernel(const int* __restrict__ src, const int* __restrict__ trg,
                             const float* __restrict__ es, const float* __restrict__ et,
                             const float* __restrict__ PEt,
                             float* __restrict__ X, u16* __restrict__ Xb,
                             float* __restrict__ Y, u16* __restrict__ Ybf)
{
    int gtok = blockIdx.x;
    int d = threadIdx.x;
    bool dec = gtok >= MTOK;
    int tok = dec ? gtok - MTOK : gtok;
    int pos = tok & (SS - 1);
    int id = (dec ? trg : src)[tok];
    const float* emb = dec ? et : es;
    float val = emb[(size_t)id * DDIM + d] * 22.62741699796952f + PEt[pos * DDIM + d];
    (dec ? Y : X)[(size_t)tok * DDIM + d] = val;
    (dec ? Ybf : Xb)[(size_t)tok * DDIM + d] = f2bf(val);
}

// ============ residual add + LayerNorm (fp32 in place, bf16 shadow out) ============
__global__ __launch_bounds__(256) void add_ln_kernel(float* __restrict__ x,
    const float* __restrict__ addv, const float* __restrict__ g,
    const float* __restrict__ bta, u16* __restrict__ xb)
{
    int row = blockIdx.x;
    int tid = threadIdx.x;
    size_t base = (size_t)row * DDIM;
    __shared__ float sbuf[4];

    float v0 = x[base + tid]       + addv[base + tid];
    float v1 = x[base + tid + 256] + addv[base + tid + 256];

    float s = v0 + v1;
    #pragma unroll
    for (int o = 32; o > 0; o >>= 1) s += __shfl_down(s, o);
    if ((tid & 63) == 0) sbuf[tid >> 6] = s;
    __syncthreads();
    float mean = (sbuf[0] + sbuf[1] + sbuf[2] + sbuf[3]) * (1.0f / DDIM);
    __syncthreads();

    float d0 = v0 - mean, d1 = v1 - mean;
    float ss = d0 * d0 + d1 * d1;
    #pragma unroll
    for (int o = 32; o > 0; o >>= 1) ss += __shfl_down(ss, o);
    if ((tid & 63) == 0) sbuf[tid >> 6] = ss;
    __syncthreads();
    float var = (sbuf[0] + sbuf[1] + sbuf[2] + sbuf[3]) * (1.0f / DDIM);
    float inv = rsqrtf(var + 1e-5f);

    float o0 = d0 * inv * g[tid]       + bta[tid];
    float o1 = d1 * inv * g[tid + 256] + bta[tid + 256];
    x[base + tid] = o0;
    x[base + tid + 256] = o1;
    xb[base + tid] = f2bf(o0);
    xb[base + tid + 256] = f2bf(o1);
}

// ============ split-K reducer + bias + residual add + LayerNorm ============
__global__ __launch_bounds__(256) void add_ln_red(float* __restrict__ x,
    const float* __restrict__ part, const float* __restrict__ bias,
    const float* __restrict__ g, const float* __restrict__ bta, u16* __restrict__ xb)
{
    int row = blockIdx.x;
    int tid = threadIdx.x;
    size_t base = (size_t)row * DDIM;
    __shared__ float sbuf[4];

    float v0 = x[base + tid]       + bias[tid];
    float v1 = x[base + tid + 256] + bias[tid + 256];
    #pragma unroll
    for (int s4 = 0; s4 < 4; s4++) {
        v0 += part[s4 * MSZE + base + tid];
        v1 += part[s4 * MSZE + base + tid + 256];
    }

    float s = v0 + v1;
    #pragma unroll
    for (int o = 32; o > 0; o >>= 1) s += __shfl_down(s, o);
    if ((tid & 63) == 0) sbuf[tid >> 6] = s;
    __syncthreads();
    float mean = (sbuf[0] + sbuf[1] + sbuf[2] + sbuf[3]) * (1.0f / DDIM);
    __syncthreads();

    float d0 = v0 - mean, d1 = v1 - mean;
    float ss = d0 * d0 + d1 * d1;
    #pragma unroll
    for (int o = 32; o > 0; o >>= 1) ss += __shfl_down(ss, o);
    if ((tid & 63) == 0) sbuf[tid >> 6] = ss;
    __syncthreads();
    float var = (sbuf[0] + sbuf[1] + sbuf[2] + sbuf[3]) * (1.0f / DDIM);
    float inv = rsqrtf(var + 1e-5f);

    float o0 = d0 * inv * g[tid]       + bta[tid];
    float o1 = d1 * inv * g[tid + 256] + bta[tid + 256];
    x[base + tid] = o0;
    x[base + tid + 256] = o1;
    xb[base + tid] = f2bf(o0);
    xb[base + tid + 256] = f2bf(o1);
}

// ======================= host orchestration =======================
extern "C" void kernel_launch(void* const* d_in, const int* in_sizes, int n_in,
                              void* d_out, int out_size, void* d_ws, size_t ws_size,
                              hipStream_t stream)
{
    (void)in_sizes; (void)n_in; (void)out_size;

    const int*   src      = (const int*)  d_in[0];
    const int*   trg      = (const int*)  d_in[1];
    const float* emb_src  = (const float*)d_in[2];
    const float* emb_trg  = (const float*)d_in[3];
    const float* enc_wq   = (const float*)d_in[4];
    const float* enc_wk   = (const float*)d_in[5];
    const float* enc_wv   = (const float*)d_in[6];
    const float* enc_wo   = (const float*)d_in[7];
    const float* enc_ln1g = (const float*)d_in[8];
    const float* enc_ln1b = (const float*)d_in[9];
    const float* enc_w1   = (const float*)d_in[10];
    const float* enc_b1   = (const float*)d_in[11];
    const float* enc_w2   = (const float*)d_in[12];
    const float* enc_b2   = (const float*)d_in[13];
    const float* enc_ln2g = (const float*)d_in[14];
    const float* enc_ln2b = (const float*)d_in[15];
    const float* dec_wq   = (const float*)d_in[16];
    const float* dec_wk   = (const float*)d_in[17];
    const float* dec_wv   = (const float*)d_in[18];
    const float* dec_wo   = (const float*)d_in[19];
    const float* dec_ln1g = (const float*)d_in[20];
    const float* dec_ln1b = (const float*)d_in[21];
    const float* dec_cq   = (const float*)d_in[22];
    const float* dec_ck   = (const float*)d_in[23];
    const float* dec_cv   = (const float*)d_in[24];
    const float* dec_co   = (const float*)d_in[25];
    const float* dec_ln2g = (const float*)d_in[26];
    const float* dec_ln2b = (const float*)d_in[27];
    const float* dec_w1   = (const float*)d_in[28];
    const float* dec_b1   = (const float*)d_in[29];
    const float* dec_w2   = (const float*)d_in[30];
    const float* dec_b2   = (const float*)d_in[31];
    const float* dec_ln3g = (const float*)d_in[32];
    const float* dec_ln3b = (const float*)d_in[33];
    const float* proj     = (const float*)d_in[34];

    float* OUT = (float*)d_out;
    char* base = (char*)d_ws;

    size_t off = 0;
    auto carve = [&](size_t bytes) { char* p = base + off; off += (bytes + 255) & ~(size_t)255; return p; };

    float* X      = (float*)carve(MSZE * 4);
    float* Yb     = (float*)carve(MSZE * 4);
    float* T1     = (float*)carve(MSZE * 4);
    u16*   Xb     = (u16*)  carve(MSZE * 2);
    u16*   Ybf    = (u16*)  carve(MSZE * 2);
    u16*   QKb    = (u16*)  carve((size_t)MTOK * 1024 * 2);
    u16*   Vt     = (u16*)  carve((size_t)512 * MTOK * 2);
    u16*   CTX    = (u16*)  carve(MSZE * 2);
    u16*   HFF    = (u16*)  carve((size_t)MTOK * FFN * 2);
    u16*   Kcr    = (u16*)  carve((size_t)NL * MTOK * 512 * 2);
    u16*   Vtc    = (u16*)  carve((size_t)NL * 512 * MTOK * 2);
    u16*   projT  = (u16*)  carve((size_t)NVOC * 512 * 2);
    float* PEt    = (float*)carve((size_t)SS * DDIM * 4);
    float* Tp4    = (float*)carve((size_t)4 * MSZE * 4);       // split-K partials (16 MB)

    const size_t WFULL_B = (size_t)12 * WBLK * 2;
    bool full = (ws_size >= off + WFULL_B);
    u16* Wreg = (u16*)carve(full ? WFULL_B : (size_t)WBLK * 2);

    auto T = [&](const float* s, u16* d, int Kd, int Nd, size_t ss, size_t ds, int L) {
        transp<<<dim3(Nd / 64, Kd / 64, L), 256, 0, stream>>>(s, d, Nd, Kd, ss, ds);
    };

    // ---- one-time prep ----
    pe_kernel<<<SS, DDIM, 0, stream>>>(PEt);
    T(proj, projT, 512, NVOC, 0, 0, 1);
    if (full) {
        transpW<<<dim3(8, 8, 12 * NL), 256, 0, stream>>>(
            enc_wq, enc_wk, enc_wv, enc_wo,
            dec_wq, dec_wk, dec_wv, dec_wo,
            dec_cq, dec_ck, dec_cv, dec_co, Wreg);
        transpF1<<<dim3(32, 8, 2 * NL), 256, 0, stream>>>(enc_w1, dec_w1, Wreg);
        transpF2<<<dim3(8, 32, 2 * NL), 256, 0, stream>>>(enc_w2, dec_w2, Wreg);
    }
    // merged embeddings (no dependency on encoder)
    embed_kernel<<<2 * MTOK, DDIM, 0, stream>>>(src, trg, emb_src, emb_trg, PEt, X, Xb, Yb, Ybf);

    // self-attention block: (QK-proj ∥ V^T-proj) dual 128² GEMM + flash + O-proj -> T1
    auto self_attn = [&](const u16* xsrc, const u16* wb, const int* mask_ids, int causal) {
        mgemm_dual<128, 128><<<dim3(192), 256, 0, stream>>>(
            xsrc, 512, wb + OFF_QK, 512, QKb, 1024, 8, 128,
            wb + OFF_WV, 512, xsrc, 512, Vt, MTOK, 16,
            512);
        if (causal)
            flash_attn<1><<<dim3(4, 32), 512, 0, stream>>>(QKb, 1024, QKb + 512, 1024, Vt, CTX, mask_ids);
        else
            flash_attn<0><<<dim3(4, 32), 512, 0, stream>>>(QKb, 1024, QKb + 512, 1024, Vt, CTX, mask_ids);
        mgemm<64, 64, 0, 0, 0><<<dim3(8, 32, 1), 256, 0, stream>>>(
            CTX, 512, 0, 0, wb + OFF_WO, 512, 0, 0, T1, 512, 0, 0, 512, nullptr);
    };

    // FFN: W1 GEMM (128², relu+bias) then W2 split-K(4x512) 128² -> Tp4, reduced in add_ln_red
    auto ffn = [&](const u16* xsrc, const u16* wb, const float* b1) {
        mgemm<128, 128, 1, 1, 1><<<dim3(16, 16, 1), 256, 0, stream>>>(
            xsrc, 512, 0, 0, wb + OFF_W1, 512, 0, 0, HFF, FFN, 0, 0, 512, b1);
        mgemm<128, 128, 0, 0, 0><<<dim3(4, 16, 4), 256, 0, stream>>>(
            HFF, 2048, 0, 512, wb + OFF_W2, 2048, 0, 512,
            Tp4, 512, 0, MSZE, 512, nullptr);
    };

    const size_t M2 = M2CNT, MF1 = MF1CNT;

    // ---- encoder ----
    for (int l = 0; l < NL; l++) {
        u16* wb;
        if (full) wb = Wreg + (size_t)l * WBLK;
        else {
            wb = Wreg;
            T(enc_wq + l * M2,  wb + OFF_QK,          512, 512,  0, 0, 1);
            T(enc_wk + l * M2,  wb + OFF_QK + M2,     512, 512,  0, 0, 1);
            T(enc_wv + l * M2,  wb + OFF_WV,          512, 512,  0, 0, 1);
            T(enc_wo + l * M2,  wb + OFF_WO,          512, 512,  0, 0, 1);
            T(enc_w1 + l * MF1, wb + OFF_W1,          512, 2048, 0, 0, 1);
            T(enc_w2 + l * MF1, wb + OFF_W2,          2048, 512, 0, 0, 1);
        }
        self_attn(Xb, wb, src, 0);
        add_ln_kernel<<<MTOK, 256, 0, stream>>>(X, T1, enc_ln1g + l * DDIM, enc_ln1b + l * DDIM, Xb);
        ffn(Xb, wb, enc_b1 + l * FFN);
        add_ln_red<<<MTOK, 256, 0, stream>>>(X, Tp4, enc_b2 + l * DDIM,
                                             enc_ln2g + l * DDIM, enc_ln2b + l * DDIM, Xb);
    }

    // ---- cross-attention K / V^T for all 6 decoder layers (batched over z) ----
    if (full) {
        u16* Wd = Wreg + (size_t)NL * WBLK;
        mgemm<128, 128, 1, 0, 0><<<dim3(4, 16, NL), 256, 0, stream>>>(
            Xb, 512, 0, 0, Wd + OFF_CK, 512, 0, WBLK, Kcr, 512, 0, (size_t)MTOK * 512, 512, nullptr);
        mgemm<128, 128, 1, 0, 0><<<dim3(16, 4, NL), 256, 0, stream>>>(
            Wd + OFF_CV, 512, 0, WBLK, Xb, 512, 0, 0, Vtc, MTOK, 0, (size_t)512 * MTOK, 512, nullptr);
    }

    // ---- decoder ----
    for (int l = 0; l < NL; l++) {
        u16* wb;
        if (full) wb = Wreg + (size_t)(NL + l) * WBLK;
        else {
            wb = Wreg;
            T(dec_wq + l * M2,  wb + OFF_QK,          512, 512,  0, 0, 1);
            T(dec_wk + l * M2,  wb + OFF_QK + M2,     512, 512,  0, 0, 1);
            T(dec_wv + l * M2,  wb + OFF_WV,          512, 512,  0, 0, 1);
            T(dec_wo + l * M2,  wb + OFF_WO,          512, 512,  0, 0, 1);
            T(dec_cq + l * M2,  wb + OFF_CQ,          512, 512,  0, 0, 1);
            T(dec_ck + l * M2,  wb + OFF_CK,          512, 512,  0, 0, 1);
            T(dec_cv + l * M2,  wb + OFF_CV,          512, 512,  0, 0, 1);
            T(dec_co + l * M2,  wb + OFF_CO,          512, 512,  0, 0, 1);
            T(dec_w1 + l * MF1, wb + OFF_W1,          512, 2048, 0, 0, 1);
            T(dec_w2 + l * MF1, wb + OFF_W2,          2048, 512, 0, 0, 1);
            mgemm<128, 128, 1, 0, 0><<<dim3(4, 16, 1), 256, 0, stream>>>(
                Xb, 512, 0, 0, wb + OFF_CK, 512, 0, 0, Kcr + (size_t)l * MTOK * 512, 512, 0, 0, 512, nullptr);
            mgemm<128, 128, 1, 0, 0><<<dim3(16, 4, 1), 256, 0, stream>>>(
                wb + OFF_CV, 512, 0, 0, Xb, 512, 0, 0, Vtc + (size_t)l * 512 * MTOK, MTOK, 0, 0, 512, nullptr);
        }
        // masked self-attention
        self_attn(Ybf, wb, trg, 1);
        add_ln_kernel<<<MTOK, 256, 0, stream>>>(Yb, T1, dec_ln1g + l * DDIM, dec_ln1b + l * DDIM, Ybf);
        // cross-attention
        mgemm<64, 64, 1, 0, 0><<<dim3(8, 32, 1), 256, 0, stream>>>(
            Ybf, 512, 0, 0, wb + OFF_CQ, 512, 0, 0, QKb, 1024, 0, 0, 512, nullptr);
        flash_attn<0><<<dim3(4, 32), 512, 0, stream>>>(
            QKb, 1024, Kcr + (size_t)l * MTOK * 512, 512, Vtc + (size_t)l * 512 * MTOK, CTX, src);
        mgemm<64, 64, 0, 0, 0><<<dim3(8, 32, 1), 256, 0, stream>>>(
            CTX, 512, 0, 0, wb + OFF_CO, 512, 0, 0, T1, 512, 0, 0, 512, nullptr);
        add_ln_kernel<<<MTOK, 256, 0, stream>>>(Yb, T1, dec_ln2g + l * DDIM, dec_ln2b + l * DDIM, Ybf);
        // FFN
        ffn(Ybf, wb, dec_b1 + l * FFN);
        add_ln_red<<<MTOK, 256, 0, stream>>>(Yb, Tp4, dec_b2 + l * DDIM,
                                             dec_ln3g + l * DDIM, dec_ln3b + l * DDIM, Ybf);
    }

    // ---- final vocab projection (XCD-swizzled) ----
    mgemm<128, 128, 0, 0, 0, 1><<<dim3(NVOC / 128, 16, 1), 256, 0, stream>>>(
        Ybf, 512, 0, 0, projT, 512, 0, 0, OUT, NVOC, 0, 0, 512, nullptr);
}